// Round 1
// baseline (499.945 us; speedup 1.0000x reference)
//
#include <hip/hip_runtime.h>

#define H_DIM 2048
#define EI_DIM 2048
#define T_TOK 4096
#define NEXP 4
#define MAXTILES 36
#define MAXROWS (MAXTILES * 128)

typedef __attribute__((ext_vector_type(4))) float f32x4;
typedef __attribute__((ext_vector_type(8))) short bf16x8;
typedef __attribute__((ext_vector_type(4))) short bf16x4;

__device__ __forceinline__ short f2bf(float f) {
  unsigned u = __builtin_bit_cast(unsigned, f);
  u += 0x7fffu + ((u >> 16) & 1u);
  return (short)(u >> 16);
}

// ---------------- routing: deterministic expert bucketing ----------------
// 1 block x 256 threads; each thread owns 16 consecutive tokens.
__global__ void route_kernel(const void* __restrict__ token_ids,
                             int* __restrict__ meta, int* __restrict__ row2tok) {
  __shared__ unsigned long long wtot[4];
  __shared__ int seg[5];
  const int tid = threadIdx.x;
  const int lane = tid & 63;
  const int wv = tid >> 6;

  // init all padded rows to -1
  for (int i = tid; i < MAXROWS; i += 256) row2tok[i] = -1;

  // detect int32 vs int64 token buffer: int64 -> odd 32-bit words are zero
  const int* ti32 = (const int*)token_ids;
  bool is64 = true;
  for (int i = 0; i < 16; ++i)
    if (ti32[2 * i + 1] != 0) is64 = false;

  // count experts for my 16 tokens; pack 4x16-bit counters
  const int base = tid * 16;
  unsigned long long pack = 0ULL;
  unsigned eps = 0;  // 2 bits per token
  for (int i = 0; i < 16; ++i) {
    long long v = is64 ? ((const long long*)token_ids)[base + i]
                       : (long long)ti32[base + i];
    if (v < 0) v = 0;
    if (v > 99999) v = 99999;
    int e = (int)(v & 3);
    eps |= (unsigned)e << (2 * i);
    pack += 1ULL << (16 * e);
  }

  // wave-inclusive scan of packed counters
  unsigned long long incl = pack;
  for (int off = 1; off < 64; off <<= 1) {
    unsigned long long up = __shfl_up(incl, off, 64);
    if (lane >= off) incl += up;
  }
  if (lane == 63) wtot[wv] = incl;
  __syncthreads();

  unsigned long long waveBase = 0, grand = 0;
  for (int w = 0; w < 4; ++w) {
    if (w < wv) waveBase += wtot[w];
    grand += wtot[w];
  }
  const unsigned long long exclu = waveBase + incl - pack;

  if (tid == 0) {
    int s = 0, t = 0;
    for (int e = 0; e < 4; ++e) {
      seg[e] = s;
      int cnt = (int)((grand >> (16 * e)) & 0xffff);
      int tiles = (cnt + 127) >> 7;
      for (int k = 0; k < tiles; ++k) meta[1 + t + k] = e;
      t += tiles;
      s += tiles * 128;
    }
    seg[4] = s;
    meta[0] = t;
  }
  __syncthreads();

  int cur[4];
  for (int e = 0; e < 4; ++e)
    cur[e] = seg[e] + (int)((exclu >> (16 * e)) & 0xffff);
  for (int i = 0; i < 16; ++i) {
    int e = (int)((eps >> (2 * i)) & 3);
    row2tok[cur[e]] = base + i;
    cur[e]++;
  }
}

// ---------------- gather: permuted X rows -> bf16 ----------------
__global__ void gather_kernel(const float* __restrict__ hidden,
                              const int* __restrict__ row2tok,
                              short* __restrict__ xperm) {
  const int r = blockIdx.x;
  const int tok = row2tok[r];
  const int tid = threadIdx.x;  // 256; 8 floats each
  f32x4 a = {0.f, 0.f, 0.f, 0.f}, b = {0.f, 0.f, 0.f, 0.f};
  if (tok >= 0) {
    const f32x4* src = (const f32x4*)(hidden + (size_t)tok * H_DIM + 8 * tid);
    a = src[0];
    b = src[1];
  }
  bf16x8 v;
  v[0] = f2bf(a[0]); v[1] = f2bf(a[1]); v[2] = f2bf(a[2]); v[3] = f2bf(a[3]);
  v[4] = f2bf(b[0]); v[5] = f2bf(b[1]); v[6] = f2bf(b[2]); v[7] = f2bf(b[3]);
  *(bf16x8*)(xperm + (size_t)r * H_DIM + 8 * tid) = v;
}

// ---------------- GEMM1: fused gate/up + SwiGLU -> inter (bf16) ----------------
__global__ __launch_bounds__(256, 2) void gemm1_kernel(
    const short* __restrict__ xperm, const float* __restrict__ gateW,
    const float* __restrict__ upW, const int* __restrict__ meta,
    short* __restrict__ inter) {
  const int tm = blockIdx.x;
  if (tm >= meta[0]) return;
  const int e = meta[1 + tm];
  const int rowBase = tm * 128;
  const int colBase = blockIdx.y * 128;
  const float* gW = gateW + (size_t)e * H_DIM * EI_DIM;
  const float* uW = upW + (size_t)e * H_DIM * EI_DIM;

  __shared__ short As[128 * 64];
  __shared__ short Bg[128 * 64];
  __shared__ short Bu[128 * 64];

  const int tid = threadIdx.x;
  const int lane = tid & 63;
  const int wv = tid >> 6;
  const int wr = (wv >> 1) * 64;
  const int wc = (wv & 1) * 64;

  f32x4 accG[4][4] = {};
  f32x4 accU[4][4] = {};

  const int ar = tid >> 3;          // A stage row (0..31), +32 per pass
  const int ak = (tid & 7) * 8;     // A stage k (bf16 elems)
  const int bn = (tid & 31) * 4;    // B stage col
  const int bk = (tid >> 5) * 4;    // B stage k

  for (int k0 = 0; k0 < H_DIM; k0 += 64) {
    // global loads to registers
    bf16x8 av[4];
#pragma unroll
    for (int p = 0; p < 4; ++p) {
      int r = ar + p * 32;
      av[p] = *(const bf16x8*)(xperm + (size_t)(rowBase + r) * H_DIM + k0 + ak);
    }
    f32x4 gv[2][4], uv[2][4];
#pragma unroll
    for (int p = 0; p < 2; ++p) {
      int kk = k0 + bk + p * 32;
#pragma unroll
      for (int i = 0; i < 4; ++i) {
        gv[p][i] = *(const f32x4*)(gW + (size_t)(kk + i) * EI_DIM + colBase + bn);
        uv[p][i] = *(const f32x4*)(uW + (size_t)(kk + i) * EI_DIM + colBase + bn);
      }
    }
    __syncthreads();
    // LDS writes (swizzled)
#pragma unroll
    for (int p = 0; p < 4; ++p) {
      int r = ar + p * 32;
      int idx = (r * 64 + ak) ^ ((r & 7) << 3);
      *(bf16x8*)(As + idx) = av[p];
    }
#pragma unroll
    for (int p = 0; p < 2; ++p) {
      int kk = bk + p * 32;
#pragma unroll
      for (int j = 0; j < 4; ++j) {
        int rowp = bn + j;
        int idx = (rowp * 64 + kk) ^ ((rowp & 7) << 3);
        bf16x4 vg, vu;
        vg[0] = f2bf(gv[p][0][j]); vg[1] = f2bf(gv[p][1][j]);
        vg[2] = f2bf(gv[p][2][j]); vg[3] = f2bf(gv[p][3][j]);
        vu[0] = f2bf(uv[p][0][j]); vu[1] = f2bf(uv[p][1][j]);
        vu[2] = f2bf(uv[p][2][j]); vu[3] = f2bf(uv[p][3][j]);
        *(bf16x4*)(Bg + idx) = vg;
        *(bf16x4*)(Bu + idx) = vu;
      }
    }
    __syncthreads();
    // MFMA
#pragma unroll
    for (int kk = 0; kk < 64; kk += 32) {
      const int kb = kk + ((lane >> 4) << 3);
      bf16x8 af[4], bgf[4], buf_[4];
#pragma unroll
      for (int m = 0; m < 4; ++m) {
        int r = wr + m * 16 + (lane & 15);
        af[m] = *(const bf16x8*)(As + ((r * 64 + kb) ^ ((r & 7) << 3)));
      }
#pragma unroll
      for (int n = 0; n < 4; ++n) {
        int c = wc + n * 16 + (lane & 15);
        int idx = (c * 64 + kb) ^ ((c & 7) << 3);
        bgf[n] = *(const bf16x8*)(Bg + idx);
        buf_[n] = *(const bf16x8*)(Bu + idx);
      }
#pragma unroll
      for (int m = 0; m < 4; ++m)
#pragma unroll
        for (int n = 0; n < 4; ++n) {
          accG[m][n] = __builtin_amdgcn_mfma_f32_16x16x32_bf16(
              af[m], bgf[n], accG[m][n], 0, 0, 0);
          accU[m][n] = __builtin_amdgcn_mfma_f32_16x16x32_bf16(
              af[m], buf_[n], accU[m][n], 0, 0, 0);
        }
    }
  }
  // epilogue: silu(g)*u -> inter (bf16)
#pragma unroll
  for (int m = 0; m < 4; ++m)
#pragma unroll
    for (int n = 0; n < 4; ++n) {
      int c = colBase + wc + n * 16 + (lane & 15);
#pragma unroll
      for (int j = 0; j < 4; ++j) {
        int r = rowBase + wr + m * 16 + ((lane >> 4) << 2) + j;
        float g = accG[m][n][j], u = accU[m][n][j];
        float s = g / (1.0f + __expf(-g));
        inter[(size_t)r * EI_DIM + c] = f2bf(s * u);
      }
    }
}

// ---------------- GEMM2: inter @ down -> scatter to out ----------------
__global__ __launch_bounds__(256, 2) void gemm2_kernel(
    const short* __restrict__ inter, const float* __restrict__ downW,
    const int* __restrict__ meta, const int* __restrict__ row2tok,
    float* __restrict__ out) {
  const int tm = blockIdx.x;
  if (tm >= meta[0]) return;
  const int e = meta[1 + tm];
  const int rowBase = tm * 128;
  const int colBase = blockIdx.y * 128;
  const float* dW = downW + (size_t)e * EI_DIM * H_DIM;

  __shared__ short As[128 * 64];
  __shared__ short Bs[128 * 64];

  const int tid = threadIdx.x;
  const int lane = tid & 63;
  const int wv = tid >> 6;
  const int wr = (wv >> 1) * 64;
  const int wc = (wv & 1) * 64;

  f32x4 acc[4][4] = {};

  const int ar = tid >> 3;
  const int ak = (tid & 7) * 8;
  const int bn = (tid & 31) * 4;
  const int bk = (tid >> 5) * 4;

  for (int k0 = 0; k0 < EI_DIM; k0 += 64) {
    bf16x8 av[4];
#pragma unroll
    for (int p = 0; p < 4; ++p) {
      int r = ar + p * 32;
      av[p] = *(const bf16x8*)(inter + (size_t)(rowBase + r) * EI_DIM + k0 + ak);
    }
    f32x4 dv[2][4];
#pragma unroll
    for (int p = 0; p < 2; ++p) {
      int kk = k0 + bk + p * 32;
#pragma unroll
      for (int i = 0; i < 4; ++i)
        dv[p][i] = *(const f32x4*)(dW + (size_t)(kk + i) * H_DIM + colBase + bn);
    }
    __syncthreads();
#pragma unroll
    for (int p = 0; p < 4; ++p) {
      int r = ar + p * 32;
      int idx = (r * 64 + ak) ^ ((r & 7) << 3);
      *(bf16x8*)(As + idx) = av[p];
    }
#pragma unroll
    for (int p = 0; p < 2; ++p) {
      int kk = bk + p * 32;
#pragma unroll
      for (int j = 0; j < 4; ++j) {
        int rowp = bn + j;
        int idx = (rowp * 64 + kk) ^ ((rowp & 7) << 3);
        bf16x4 vd;
        vd[0] = f2bf(dv[p][0][j]); vd[1] = f2bf(dv[p][1][j]);
        vd[2] = f2bf(dv[p][2][j]); vd[3] = f2bf(dv[p][3][j]);
        *(bf16x4*)(Bs + idx) = vd;
      }
    }
    __syncthreads();
#pragma unroll
    for (int kk = 0; kk < 64; kk += 32) {
      const int kb = kk + ((lane >> 4) << 3);
      bf16x8 af[4], bf_[4];
#pragma unroll
      for (int m = 0; m < 4; ++m) {
        int r = wr + m * 16 + (lane & 15);
        af[m] = *(const bf16x8*)(As + ((r * 64 + kb) ^ ((r & 7) << 3)));
      }
#pragma unroll
      for (int n = 0; n < 4; ++n) {
        int c = wc + n * 16 + (lane & 15);
        bf_[n] = *(const bf16x8*)(Bs + ((c * 64 + kb) ^ ((c & 7) << 3)));
      }
#pragma unroll
      for (int m = 0; m < 4; ++m)
#pragma unroll
        for (int n = 0; n < 4; ++n)
          acc[m][n] = __builtin_amdgcn_mfma_f32_16x16x32_bf16(
              af[m], bf_[n], acc[m][n], 0, 0, 0);
    }
  }
  // epilogue: scatter rows to out by token
#pragma unroll
  for (int m = 0; m < 4; ++m)
#pragma unroll
    for (int j = 0; j < 4; ++j) {
      int r = rowBase + wr + m * 16 + ((lane >> 4) << 2) + j;
      int tok = row2tok[r];
      if (tok >= 0) {
        float* orow = out + (size_t)tok * H_DIM + colBase + wc + (lane & 15);
#pragma unroll
        for (int n = 0; n < 4; ++n) orow[n * 16] = acc[m][n][j];
      }
    }
}

extern "C" void kernel_launch(void* const* d_in, const int* in_sizes, int n_in,
                              void* d_out, int out_size, void* d_ws,
                              size_t ws_size, hipStream_t stream) {
  const float* hidden = (const float*)d_in[0];
  const void* token_ids = d_in[1];
  const float* gateW = (const float*)d_in[2];
  const float* upW = (const float*)d_in[3];
  const float* downW = (const float*)d_in[4];
  float* out = (float*)d_out;

  int* meta = (int*)d_ws;
  int* row2tok = meta + 64;
  short* xperm = (short*)((char*)d_ws + 32768);
  short* inter = xperm + (size_t)MAXROWS * H_DIM;

  route_kernel<<<1, 256, 0, stream>>>(token_ids, meta, row2tok);
  gather_kernel<<<MAXROWS, 256, 0, stream>>>(hidden, row2tok, xperm);
  gemm1_kernel<<<dim3(MAXTILES, EI_DIM / 128), 256, 0, stream>>>(
      xperm, gateW, upW, meta, inter);
  gemm2_kernel<<<dim3(MAXTILES, H_DIM / 128), 256, 0, stream>>>(
      inter, downW, meta, row2tok, out);
}

// Round 2
// 220.648 us; speedup vs baseline: 2.2658x; 2.2658x over previous
//
#include <hip/hip_runtime.h>

#define H_DIM 2048
#define EI_DIM 2048
#define NEXP 4
#define MAXTILES 36
#define MAXROWS (MAXTILES * 128)
#define TILE_SHORTS 8192  // 64k x 128 bf16 = 16KB tile
#define KB1 32            // k-blocks for gemm1 (H/64)
#define KB2 32            // k-blocks for gemm2 (EI/64)
#define NB 16             // 128-col blocks per 2048

typedef __attribute__((ext_vector_type(4))) float f32x4;
typedef __attribute__((ext_vector_type(8))) short bf16x8;
typedef __attribute__((ext_vector_type(4))) short bf16x4;

__device__ __forceinline__ short f2bf(float f) {
  unsigned u = __builtin_bit_cast(unsigned, f);
  u += 0x7fffu + ((u >> 16) & 1u);
  return (short)(u >> 16);
}

__device__ __forceinline__ void gload16(const void* g, void* l) {
  __builtin_amdgcn_global_load_lds(
      (const __attribute__((address_space(1))) unsigned*)g,
      (__attribute__((address_space(3))) unsigned*)l, 16, 0, 0);
}

// ---------------- routing: deterministic expert bucketing ----------------
__global__ void route_kernel(const void* __restrict__ token_ids,
                             int* __restrict__ meta, int* __restrict__ row2tok) {
  __shared__ unsigned long long wtot[4];
  __shared__ int seg[5];
  const int tid = threadIdx.x;
  const int lane = tid & 63;
  const int wv = tid >> 6;

  for (int i = tid; i < MAXROWS; i += 256) row2tok[i] = -1;

  const int* ti32 = (const int*)token_ids;
  bool is64 = true;
  for (int i = 0; i < 16; ++i)
    if (ti32[2 * i + 1] != 0) is64 = false;

  const int base = tid * 16;
  unsigned long long pack = 0ULL;
  unsigned eps = 0;
  for (int i = 0; i < 16; ++i) {
    long long v = is64 ? ((const long long*)token_ids)[base + i]
                       : (long long)ti32[base + i];
    if (v < 0) v = 0;
    if (v > 99999) v = 99999;
    int e = (int)(v & 3);
    eps |= (unsigned)e << (2 * i);
    pack += 1ULL << (16 * e);
  }

  unsigned long long incl = pack;
  for (int off = 1; off < 64; off <<= 1) {
    unsigned long long up = __shfl_up(incl, off, 64);
    if (lane >= off) incl += up;
  }
  if (lane == 63) wtot[wv] = incl;
  __syncthreads();

  unsigned long long waveBase = 0, grand = 0;
  for (int w = 0; w < 4; ++w) {
    if (w < wv) waveBase += wtot[w];
    grand += wtot[w];
  }
  const unsigned long long exclu = waveBase + incl - pack;

  if (tid == 0) {
    int s = 0, t = 0;
    for (int e = 0; e < 4; ++e) {
      seg[e] = s;
      int cnt = (int)((grand >> (16 * e)) & 0xffff);
      int tiles = (cnt + 127) >> 7;
      for (int k = 0; k < tiles; ++k) meta[1 + t + k] = e;
      t += tiles;
      s += tiles * 128;
    }
    seg[4] = s;
    meta[0] = t;
  }
  __syncthreads();

  int cur[4];
  for (int e = 0; e < 4; ++e)
    cur[e] = seg[e] + (int)((exclu >> (16 * e)) & 0xffff);
  for (int i = 0; i < 16; ++i) {
    int e = (int)((eps >> (2 * i)) & 3);
    row2tok[cur[e]] = base + i;
    cur[e]++;
  }
}

// ======================= FAST PATH (packed layouts) =======================

// convert fp32 weights -> bf16 fragment-linear 16KB tiles
// tile id = e*(NB*32) + nb*32 + kb ; frag idx = kslot*128 + c (16B each)
__global__ __launch_bounds__(256) void convert_kernel(
    const float* __restrict__ gW, const float* __restrict__ uW,
    const float* __restrict__ dW, short* __restrict__ Pg,
    short* __restrict__ Pu, short* __restrict__ Pd) {
  const int mat = blockIdx.y;
  const float* src = mat == 0 ? gW : (mat == 1 ? uW : dW);
  short* dst = mat == 0 ? Pg : (mat == 1 ? Pu : Pd);
  const int tId = blockIdx.x;
  const int e = tId >> 9;
  const int nb = (tId >> 5) & 15;
  const int kb = tId & 31;
  const float* sb = src + (size_t)e * H_DIM * EI_DIM + (size_t)(kb * 64) * 2048 + nb * 128;
  short* db = dst + (size_t)tId * TILE_SHORTS;
  const int tid = threadIdx.x;
#pragma unroll
  for (int q = 0; q < 4; ++q) {
    int idx = q * 256 + tid;
    int ks = idx >> 7, c = idx & 127;
    const float* s = sb + (size_t)(ks * 8) * 2048 + c;
    bf16x8 v;
#pragma unroll
    for (int j = 0; j < 8; ++j) v[j] = f2bf(s[(size_t)j * 2048]);
    *(bf16x8*)(db + idx * 8) = v;
  }
}

// gather permuted X rows -> bf16 fragment-linear tiles (per tm: 32 k-tiles)
__global__ __launch_bounds__(256) void gather_pack_kernel(
    const float* __restrict__ hidden, const int* __restrict__ row2tok,
    short* __restrict__ xp) {
  const int tm = blockIdx.x;
  const int tid = threadIdx.x;
  const int row = tid & 127;
  const int tok = row2tok[tm * 128 + row];
#pragma unroll
  for (int q = 0; q < 4; ++q) {
    int it = blockIdx.y * 4 + q;               // 0..127
    int flat = it * 256 + tid;                 // frag id within tm
    int co = it * 2 + (tid >> 7);              // (kb*8 + kslot), 0..255
    bf16x8 v = {0, 0, 0, 0, 0, 0, 0, 0};
    if (tok >= 0) {
      const f32x4* s = (const f32x4*)(hidden + (size_t)tok * H_DIM + co * 8);
      f32x4 a = s[0], b = s[1];
      v[0] = f2bf(a[0]); v[1] = f2bf(a[1]); v[2] = f2bf(a[2]); v[3] = f2bf(a[3]);
      v[4] = f2bf(b[0]); v[5] = f2bf(b[1]); v[6] = f2bf(b[2]); v[7] = f2bf(b[3]);
    }
    *(bf16x8*)(xp + (size_t)tm * (KB1 * TILE_SHORTS) + (size_t)flat * 8) = v;
  }
}

// GEMM1: fused gate/up + SwiGLU -> packed inter
__global__ __launch_bounds__(256, 2) void gemm1_kernel(
    const short* __restrict__ xp, const short* __restrict__ Pg,
    const short* __restrict__ Pu, const int* __restrict__ meta,
    short* __restrict__ inter) {
  const int b = blockIdx.x;
  const int swz = (b & 7) * 72 + (b >> 3);  // 576 % 8 == 0 -> bijective
  const int tm = swz >> 4, nb = swz & 15;
  if (tm >= meta[0]) return;
  const int e = meta[1 + tm];

  __shared__ short As[TILE_SHORTS];
  __shared__ short Bg[TILE_SHORTS];
  __shared__ short Bu[TILE_SHORTS];

  const int tid = threadIdx.x, lane = tid & 63, wv = tid >> 6;
  const int wr = (wv >> 1) * 64, wc = (wv & 1) * 64;
  const int wbase = tid & 192;

  f32x4 accG[4][4] = {};
  f32x4 accU[4][4] = {};

  const short* aB = xp + (size_t)(tm * KB1) * TILE_SHORTS;
  const short* gB = Pg + (size_t)((e * NB + nb) * KB1) * TILE_SHORTS;
  const short* uB = Pu + (size_t)((e * NB + nb) * KB1) * TILE_SHORTS;

  for (int kb = 0; kb < KB1; ++kb) {
    const size_t toff = (size_t)kb * TILE_SHORTS;
#pragma unroll
    for (int q = 0; q < 4; ++q) {
      const int idx = (q * 256 + tid) * 8;   // shorts
      const int wb = (q * 256 + wbase) * 16; // bytes, wave-uniform
      gload16(aB + toff + idx, (char*)As + wb);
      gload16(gB + toff + idx, (char*)Bg + wb);
      gload16(uB + toff + idx, (char*)Bu + wb);
    }
    asm volatile("s_waitcnt vmcnt(0)" ::: "memory");
    __syncthreads();
#pragma unroll
    for (int kk = 0; kk < 2; ++kk) {
      const int ks = kk * 4 + (lane >> 4);
      bf16x8 af[4], bgf[4], buf_[4];
#pragma unroll
      for (int m = 0; m < 4; ++m)
        af[m] = *(const bf16x8*)(As + (ks * 128 + wr + m * 16 + (lane & 15)) * 8);
#pragma unroll
      for (int n = 0; n < 4; ++n) {
        const int c = wc + n * 16 + (lane & 15);
        bgf[n] = *(const bf16x8*)(Bg + (ks * 128 + c) * 8);
        buf_[n] = *(const bf16x8*)(Bu + (ks * 128 + c) * 8);
      }
#pragma unroll
      for (int m = 0; m < 4; ++m)
#pragma unroll
        for (int n = 0; n < 4; ++n) {
          accG[m][n] = __builtin_amdgcn_mfma_f32_16x16x32_bf16(
              af[m], bgf[n], accG[m][n], 0, 0, 0);
          accU[m][n] = __builtin_amdgcn_mfma_f32_16x16x32_bf16(
              af[m], buf_[n], accU[m][n], 0, 0, 0);
        }
    }
    __syncthreads();
  }
  // epilogue: silu(g)*u -> packed inter (fragment-linear for gemm2's A)
#pragma unroll
  for (int n = 0; n < 4; ++n) {
    const int C = nb * 128 + wc + n * 16 + (lane & 15);
    const int kb2 = C >> 6, ksl = (C >> 3) & 7, kj = C & 7;
    const size_t base =
        (size_t)tm * (KB2 * TILE_SHORTS) + (size_t)kb2 * TILE_SHORTS + kj;
#pragma unroll
    for (int m = 0; m < 4; ++m)
#pragma unroll
      for (int j = 0; j < 4; ++j) {
        const int r = wr + m * 16 + ((lane >> 4) << 2) + j;
        const float g = accG[m][n][j], u = accU[m][n][j];
        const float s = g / (1.0f + __expf(-g));
        inter[base + (size_t)(ksl * 128 + r) * 8] = f2bf(s * u);
      }
  }
}

// GEMM2: packed inter @ packed down -> scatter fp32 out
__global__ __launch_bounds__(256, 3) void gemm2_kernel(
    const short* __restrict__ inter, const short* __restrict__ Pd,
    const int* __restrict__ meta, const int* __restrict__ row2tok,
    float* __restrict__ out) {
  const int b = blockIdx.x;
  const int swz = (b & 7) * 72 + (b >> 3);
  const int tm = swz >> 4, nb = swz & 15;
  if (tm >= meta[0]) return;
  const int e = meta[1 + tm];

  __shared__ short As[TILE_SHORTS];
  __shared__ short Bs[TILE_SHORTS];

  const int tid = threadIdx.x, lane = tid & 63, wv = tid >> 6;
  const int wr = (wv >> 1) * 64, wc = (wv & 1) * 64;
  const int wbase = tid & 192;

  f32x4 acc[4][4] = {};

  const short* aB = inter + (size_t)(tm * KB2) * TILE_SHORTS;
  const short* dB = Pd + (size_t)((e * NB + nb) * KB2) * TILE_SHORTS;

  for (int kb = 0; kb < KB2; ++kb) {
    const size_t toff = (size_t)kb * TILE_SHORTS;
#pragma unroll
    for (int q = 0; q < 4; ++q) {
      const int idx = (q * 256 + tid) * 8;
      const int wb = (q * 256 + wbase) * 16;
      gload16(aB + toff + idx, (char*)As + wb);
      gload16(dB + toff + idx, (char*)Bs + wb);
    }
    asm volatile("s_waitcnt vmcnt(0)" ::: "memory");
    __syncthreads();
#pragma unroll
    for (int kk = 0; kk < 2; ++kk) {
      const int ks = kk * 4 + (lane >> 4);
      bf16x8 af[4], bf_[4];
#pragma unroll
      for (int m = 0; m < 4; ++m)
        af[m] = *(const bf16x8*)(As + (ks * 128 + wr + m * 16 + (lane & 15)) * 8);
#pragma unroll
      for (int n = 0; n < 4; ++n)
        bf_[n] = *(const bf16x8*)(Bs + (ks * 128 + wc + n * 16 + (lane & 15)) * 8);
#pragma unroll
      for (int m = 0; m < 4; ++m)
#pragma unroll
        for (int n = 0; n < 4; ++n)
          acc[m][n] = __builtin_amdgcn_mfma_f32_16x16x32_bf16(
              af[m], bf_[n], acc[m][n], 0, 0, 0);
    }
    __syncthreads();
  }
#pragma unroll
  for (int m = 0; m < 4; ++m)
#pragma unroll
    for (int j = 0; j < 4; ++j) {
      const int r = tm * 128 + wr + m * 16 + ((lane >> 4) << 2) + j;
      const int tok = row2tok[r];
      if (tok >= 0) {
        float* orow = out + (size_t)tok * H_DIM + nb * 128 + wc + (lane & 15);
#pragma unroll
        for (int n = 0; n < 4; ++n) orow[n * 16] = acc[m][n][j];
      }
    }
}

// ======================= FALLBACK (round-1 kernels) =======================

__global__ void gather_fb_kernel(const float* __restrict__ hidden,
                                 const int* __restrict__ row2tok,
                                 short* __restrict__ xperm) {
  const int r = blockIdx.x;
  const int tok = row2tok[r];
  const int tid = threadIdx.x;
  f32x4 a = {0.f, 0.f, 0.f, 0.f}, b = {0.f, 0.f, 0.f, 0.f};
  if (tok >= 0) {
    const f32x4* src = (const f32x4*)(hidden + (size_t)tok * H_DIM + 8 * tid);
    a = src[0];
    b = src[1];
  }
  bf16x8 v;
  v[0] = f2bf(a[0]); v[1] = f2bf(a[1]); v[2] = f2bf(a[2]); v[3] = f2bf(a[3]);
  v[4] = f2bf(b[0]); v[5] = f2bf(b[1]); v[6] = f2bf(b[2]); v[7] = f2bf(b[3]);
  *(bf16x8*)(xperm + (size_t)r * H_DIM + 8 * tid) = v;
}

__global__ __launch_bounds__(256, 2) void gemm1_fb_kernel(
    const short* __restrict__ xperm, const float* __restrict__ gateW,
    const float* __restrict__ upW, const int* __restrict__ meta,
    short* __restrict__ inter) {
  const int tm = blockIdx.x;
  if (tm >= meta[0]) return;
  const int e = meta[1 + tm];
  const int rowBase = tm * 128;
  const int colBase = blockIdx.y * 128;
  const float* gW = gateW + (size_t)e * H_DIM * EI_DIM;
  const float* uW = upW + (size_t)e * H_DIM * EI_DIM;

  __shared__ short As[128 * 64];
  __shared__ short Bg[128 * 64];
  __shared__ short Bu[128 * 64];

  const int tid = threadIdx.x;
  const int lane = tid & 63;
  const int wv = tid >> 6;
  const int wr = (wv >> 1) * 64;
  const int wc = (wv & 1) * 64;

  f32x4 accG[4][4] = {};
  f32x4 accU[4][4] = {};

  const int ar = tid >> 3;
  const int ak = (tid & 7) * 8;
  const int bn = (tid & 31) * 4;
  const int bk = (tid >> 5) * 4;

  for (int k0 = 0; k0 < H_DIM; k0 += 64) {
    bf16x8 av[4];
#pragma unroll
    for (int p = 0; p < 4; ++p) {
      int r = ar + p * 32;
      av[p] = *(const bf16x8*)(xperm + (size_t)(rowBase + r) * H_DIM + k0 + ak);
    }
    f32x4 gv[2][4], uv[2][4];
#pragma unroll
    for (int p = 0; p < 2; ++p) {
      int kk = k0 + bk + p * 32;
#pragma unroll
      for (int i = 0; i < 4; ++i) {
        gv[p][i] = *(const f32x4*)(gW + (size_t)(kk + i) * EI_DIM + colBase + bn);
        uv[p][i] = *(const f32x4*)(uW + (size_t)(kk + i) * EI_DIM + colBase + bn);
      }
    }
    __syncthreads();
#pragma unroll
    for (int p = 0; p < 4; ++p) {
      int r = ar + p * 32;
      int idx = (r * 64 + ak) ^ ((r & 7) << 3);
      *(bf16x8*)(As + idx) = av[p];
    }
#pragma unroll
    for (int p = 0; p < 2; ++p) {
      int kk = bk + p * 32;
#pragma unroll
      for (int j = 0; j < 4; ++j) {
        int rowp = bn + j;
        int idx = (rowp * 64 + kk) ^ ((rowp & 7) << 3);
        bf16x4 vg, vu;
        vg[0] = f2bf(gv[p][0][j]); vg[1] = f2bf(gv[p][1][j]);
        vg[2] = f2bf(gv[p][2][j]); vg[3] = f2bf(gv[p][3][j]);
        vu[0] = f2bf(uv[p][0][j]); vu[1] = f2bf(uv[p][1][j]);
        vu[2] = f2bf(uv[p][2][j]); vu[3] = f2bf(uv[p][3][j]);
        *(bf16x4*)(Bg + idx) = vg;
        *(bf16x4*)(Bu + idx) = vu;
      }
    }
    __syncthreads();
#pragma unroll
    for (int kk = 0; kk < 64; kk += 32) {
      const int kb = kk + ((lane >> 4) << 3);
      bf16x8 af[4], bgf[4], buf_[4];
#pragma unroll
      for (int m = 0; m < 4; ++m) {
        int r = wr + m * 16 + (lane & 15);
        af[m] = *(const bf16x8*)(As + ((r * 64 + kb) ^ ((r & 7) << 3)));
      }
#pragma unroll
      for (int n = 0; n < 4; ++n) {
        int c = wc + n * 16 + (lane & 15);
        int idx = (c * 64 + kb) ^ ((c & 7) << 3);
        bgf[n] = *(const bf16x8*)(Bg + idx);
        buf_[n] = *(const bf16x8*)(Bu + idx);
      }
#pragma unroll
      for (int m = 0; m < 4; ++m)
#pragma unroll
        for (int n = 0; n < 4; ++n) {
          accG[m][n] = __builtin_amdgcn_mfma_f32_16x16x32_bf16(
              af[m], bgf[n], accG[m][n], 0, 0, 0);
          accU[m][n] = __builtin_amdgcn_mfma_f32_16x16x32_bf16(
              af[m], buf_[n], accU[m][n], 0, 0, 0);
        }
    }
  }
#pragma unroll
  for (int m = 0; m < 4; ++m)
#pragma unroll
    for (int n = 0; n < 4; ++n) {
      int c = colBase + wc + n * 16 + (lane & 15);
#pragma unroll
      for (int j = 0; j < 4; ++j) {
        int r = rowBase + wr + m * 16 + ((lane >> 4) << 2) + j;
        float g = accG[m][n][j], u = accU[m][n][j];
        float s = g / (1.0f + __expf(-g));
        inter[(size_t)r * EI_DIM + c] = f2bf(s * u);
      }
    }
}

__global__ __launch_bounds__(256, 2) void gemm2_fb_kernel(
    const short* __restrict__ inter, const float* __restrict__ downW,
    const int* __restrict__ meta, const int* __restrict__ row2tok,
    float* __restrict__ out) {
  const int tm = blockIdx.x;
  if (tm >= meta[0]) return;
  const int e = meta[1 + tm];
  const int rowBase = tm * 128;
  const int colBase = blockIdx.y * 128;
  const float* dW = downW + (size_t)e * EI_DIM * H_DIM;

  __shared__ short As[128 * 64];
  __shared__ short Bs[128 * 64];

  const int tid = threadIdx.x;
  const int lane = tid & 63;
  const int wv = tid >> 6;
  const int wr = (wv >> 1) * 64;
  const int wc = (wv & 1) * 64;

  f32x4 acc[4][4] = {};

  const int ar = tid >> 3;
  const int ak = (tid & 7) * 8;
  const int bn = (tid & 31) * 4;
  const int bk = (tid >> 5) * 4;

  for (int k0 = 0; k0 < EI_DIM; k0 += 64) {
    bf16x8 av[4];
#pragma unroll
    for (int p = 0; p < 4; ++p) {
      int r = ar + p * 32;
      av[p] = *(const bf16x8*)(inter + (size_t)(rowBase + r) * EI_DIM + k0 + ak);
    }
    f32x4 dv[2][4];
#pragma unroll
    for (int p = 0; p < 2; ++p) {
      int kk = k0 + bk + p * 32;
#pragma unroll
      for (int i = 0; i < 4; ++i)
        dv[p][i] = *(const f32x4*)(dW + (size_t)(kk + i) * H_DIM + colBase + bn);
    }
    __syncthreads();
#pragma unroll
    for (int p = 0; p < 4; ++p) {
      int r = ar + p * 32;
      int idx = (r * 64 + ak) ^ ((r & 7) << 3);
      *(bf16x8*)(As + idx) = av[p];
    }
#pragma unroll
    for (int p = 0; p < 2; ++p) {
      int kk = bk + p * 32;
#pragma unroll
      for (int j = 0; j < 4; ++j) {
        int rowp = bn + j;
        int idx = (rowp * 64 + kk) ^ ((rowp & 7) << 3);
        bf16x4 vd;
        vd[0] = f2bf(dv[p][0][j]); vd[1] = f2bf(dv[p][1][j]);
        vd[2] = f2bf(dv[p][2][j]); vd[3] = f2bf(dv[p][3][j]);
        *(bf16x4*)(Bs + idx) = vd;
      }
    }
    __syncthreads();
#pragma unroll
    for (int kk = 0; kk < 64; kk += 32) {
      const int kb = kk + ((lane >> 4) << 3);
      bf16x8 af[4], bf_[4];
#pragma unroll
      for (int m = 0; m < 4; ++m) {
        int r = wr + m * 16 + (lane & 15);
        af[m] = *(const bf16x8*)(As + ((r * 64 + kb) ^ ((r & 7) << 3)));
      }
#pragma unroll
      for (int n = 0; n < 4; ++n) {
        int c = wc + n * 16 + (lane & 15);
        bf_[n] = *(const bf16x8*)(Bs + ((c * 64 + kb) ^ ((c & 7) << 3)));
      }
#pragma unroll
      for (int m = 0; m < 4; ++m)
#pragma unroll
        for (int n = 0; n < 4; ++n)
          acc[m][n] = __builtin_amdgcn_mfma_f32_16x16x32_bf16(
              af[m], bf_[n], acc[m][n], 0, 0, 0);
    }
  }
#pragma unroll
  for (int m = 0; m < 4; ++m)
#pragma unroll
    for (int j = 0; j < 4; ++j) {
      int r = rowBase + wr + m * 16 + ((lane >> 4) << 2) + j;
      int tok = row2tok[r];
      if (tok >= 0) {
        float* orow = out + (size_t)tok * H_DIM + colBase + wc + (lane & 15);
#pragma unroll
        for (int n = 0; n < 4; ++n) orow[n * 16] = acc[m][n][j];
      }
    }
}

// ======================= launch =======================

extern "C" void kernel_launch(void* const* d_in, const int* in_sizes, int n_in,
                              void* d_out, int out_size, void* d_ws,
                              size_t ws_size, hipStream_t stream) {
  const float* hidden = (const float*)d_in[0];
  const void* token_ids = d_in[1];
  const float* gateW = (const float*)d_in[2];
  const float* upW = (const float*)d_in[3];
  const float* downW = (const float*)d_in[4];
  float* out = (float*)d_out;

  int* meta = (int*)d_ws;
  int* row2tok = meta + 64;

  const size_t wMatShorts = (size_t)NEXP * NB * KB1 * TILE_SHORTS;  // 16.78M
  const size_t xpShorts = (size_t)MAXTILES * KB1 * TILE_SHORTS;     // 9.44M
  const size_t need = 32768 + 3 * wMatShorts * 2 + 2 * xpShorts * 2;

  route_kernel<<<1, 256, 0, stream>>>(token_ids, meta, row2tok);

  if (ws_size >= need) {
    short* Pg = (short*)((char*)d_ws + 32768);
    short* Pu = Pg + wMatShorts;
    short* Pd = Pu + wMatShorts;
    short* xp = Pd + wMatShorts;
    short* inter = xp + xpShorts;

    convert_kernel<<<dim3(2048, 3), 256, 0, stream>>>(gateW, upW, downW, Pg,
                                                      Pu, Pd);
    gather_pack_kernel<<<dim3(MAXTILES, 32), 256, 0, stream>>>(hidden, row2tok,
                                                               xp);
    gemm1_kernel<<<576, 256, 0, stream>>>(xp, Pg, Pu, meta, inter);
    gemm2_kernel<<<576, 256, 0, stream>>>(inter, Pd, meta, row2tok, out);
  } else {
    short* xperm = (short*)((char*)d_ws + 32768);
    short* inter = xperm + (size_t)MAXROWS * H_DIM;

    gather_fb_kernel<<<MAXROWS, 256, 0, stream>>>(hidden, row2tok, xperm);
    gemm1_fb_kernel<<<dim3(MAXTILES, EI_DIM / 128), 256, 0, stream>>>(
        xperm, gateW, upW, meta, inter);
    gemm2_fb_kernel<<<dim3(MAXTILES, H_DIM / 128), 256, 0, stream>>>(
        inter, downW, meta, row2tok, out);
  }
}

// Round 3
// 193.321 us; speedup vs baseline: 2.5861x; 1.1414x over previous
//
#include <hip/hip_runtime.h>

#define H_DIM 2048
#define EI_DIM 2048
#define NEXP 4
#define BM 144
#define SEG 1152           // rows per expert segment (8 tiles of 144)
#define NROWS 4608         // 4 * 1152 = 32 * 144
#define NTM 32             // row tiles of 144
#define NKB 64             // K blocks of 32
#define NB 16              // 128-col blocks per 2048
#define AFRAG 576          // frags per A k-tile (4 ks * 144 r)
#define WFRAG 512          // frags per weight k-tile (4 ks * 128 c)

typedef __attribute__((ext_vector_type(4))) float f32x4;
typedef __attribute__((ext_vector_type(8))) short bf16x8;
typedef __attribute__((ext_vector_type(4))) short bf16x4;

__device__ __forceinline__ short f2bf(float f) {
  unsigned u = __builtin_bit_cast(unsigned, f);
  u += 0x7fffu + ((u >> 16) & 1u);
  return (short)(u >> 16);
}

__device__ __forceinline__ void gload16(const void* g, void* l) {
  __builtin_amdgcn_global_load_lds(
      (const __attribute__((address_space(1))) unsigned*)g,
      (__attribute__((address_space(3))) unsigned*)l, 16, 0, 0);
}

// ---------------- routing: deterministic expert bucketing ----------------
__global__ void route_kernel(const void* __restrict__ token_ids,
                             int* __restrict__ meta, int* __restrict__ row2tok) {
  __shared__ unsigned long long wtot[4];
  const int tid = threadIdx.x;
  const int lane = tid & 63;
  const int wv = tid >> 6;

  for (int i = tid; i < NROWS; i += 256) row2tok[i] = -1;

  const int* ti32 = (const int*)token_ids;
  bool is64 = true;
  for (int i = 0; i < 16; ++i)
    if (ti32[2 * i + 1] != 0) is64 = false;

  const int base = tid * 16;
  unsigned long long pack = 0ULL;
  unsigned eps = 0;
  for (int i = 0; i < 16; ++i) {
    long long v = is64 ? ((const long long*)token_ids)[base + i]
                       : (long long)ti32[base + i];
    if (v < 0) v = 0;
    if (v > 99999) v = 99999;
    int e = (int)(v & 3);
    eps |= (unsigned)e << (2 * i);
    pack += 1ULL << (16 * e);
  }

  unsigned long long incl = pack;
  for (int off = 1; off < 64; off <<= 1) {
    unsigned long long up = __shfl_up(incl, off, 64);
    if (lane >= off) incl += up;
  }
  if (lane == 63) wtot[wv] = incl;
  __syncthreads();

  unsigned long long waveBase = 0;
  for (int w = 0; w < 4; ++w)
    if (w < wv) waveBase += wtot[w];
  const unsigned long long exclu = waveBase + incl - pack;

  if (tid == 0) {
    // static 128-tile meta for the fallback path (1152 = 9*128)
    meta[0] = 36;
    for (int t = 0; t < 36; ++t) meta[1 + t] = t / 9;
  }

  int cur[4];
  for (int e = 0; e < 4; ++e)
    cur[e] = e * SEG + (int)((exclu >> (16 * e)) & 0xffff);
  for (int i = 0; i < 16; ++i) {
    int e = (int)((eps >> (2 * i)) & 3);
    int idx = cur[e]++;
    if (idx < (e + 1) * SEG) row2tok[idx] = base + i;
  }
}

// ======================= FAST PATH (packed layouts) =======================

// fp32 weights -> bf16 fragment-linear 16KB tiles: tile(e,nb,kb64) =
// [8 ks][128 c] 16B frags. Vectorized: 8x dwordx4 reads, 64B write / thread.
__global__ __launch_bounds__(256) void convert_kernel(
    const float* __restrict__ gW, const float* __restrict__ uW,
    const float* __restrict__ dW, short* __restrict__ Pg,
    short* __restrict__ Pu, short* __restrict__ Pd) {
  const int mat = blockIdx.y;
  const float* src = mat == 0 ? gW : (mat == 1 ? uW : dW);
  short* dst = mat == 0 ? Pg : (mat == 1 ? Pu : Pd);
  const int tId = blockIdx.x;
  const int e = tId >> 9;
  const int nb = (tId >> 5) & 15;
  const int kb = tId & 31;
  const int tid = threadIdx.x;
  const int ks = tid >> 5;          // 0..7
  const int c4 = (tid & 31) * 4;    // col group
  const float* sb = src + (size_t)e * H_DIM * EI_DIM +
                    (size_t)(kb * 64 + ks * 8) * 2048 + nb * 128 + c4;
  f32x4 rv[8];
#pragma unroll
  for (int j = 0; j < 8; ++j) rv[j] = *(const f32x4*)(sb + (size_t)j * 2048);
  short* db = dst + (size_t)tId * 8192 + (ks * 128 + c4) * 8;
#pragma unroll
  for (int i = 0; i < 4; ++i) {
    bf16x8 v;
#pragma unroll
    for (int j = 0; j < 8; ++j) v[j] = f2bf(rv[j][i]);
    *(bf16x8*)(db + i * 8) = v;
  }
}

// gather permuted X rows -> [tile][kb32][4 ks][144 r] bf16 frags
__global__ __launch_bounds__(256) void gather_pack_kernel(
    const float* __restrict__ hidden, const int* __restrict__ row2tok,
    short* __restrict__ xp) {
  const int tile = blockIdx.x;   // 0..31
  const int kb = blockIdx.y;     // 0..63
  const int tid = threadIdx.x;
  short* db = xp + ((size_t)tile * NKB + kb) * (AFRAG * 8);
#pragma unroll
  for (int q = 0; q < 3; ++q) {
    if (q == 2 && tid >= 64) break;
    const int idx = q * 256 + tid;          // 0..575
    const int ks = idx / 144, r = idx - ks * 144;
    const int tok = row2tok[tile * BM + r];
    bf16x8 v = {0, 0, 0, 0, 0, 0, 0, 0};
    if (tok >= 0) {
      const f32x4* s =
          (const f32x4*)(hidden + (size_t)tok * H_DIM + kb * 32 + ks * 8);
      f32x4 a = s[0], b = s[1];
      v[0] = f2bf(a[0]); v[1] = f2bf(a[1]); v[2] = f2bf(a[2]); v[3] = f2bf(a[3]);
      v[4] = f2bf(b[0]); v[5] = f2bf(b[1]); v[6] = f2bf(b[2]); v[7] = f2bf(b[3]);
    }
    *(bf16x8*)(db + idx * 8) = v;
  }
}

// GEMM1: fused gate/up + SwiGLU -> packed inter. BM=144, BN=128 (G&U), BK=32.
__global__ __launch_bounds__(256, 2) void gemm1_kernel(
    const short* __restrict__ xp, const short* __restrict__ Pg,
    const short* __restrict__ Pu, short* __restrict__ inter) {
  const int b0 = blockIdx.x;
  const int swz = (b0 & 7) * 64 + (b0 >> 3);  // 512 blocks, bijective
  const int tile = swz >> 4, nb = swz & 15;
  const int e = tile >> 3;

  __shared__ short L[2][12800];  // per buf: A 4608 | G 4096 | U 4096 shorts

  const int tid = threadIdx.x, lane = tid & 63, wv = tid >> 6;
  const int l15 = lane & 15, lks = lane >> 4;

  f32x4 accG[9][2] = {};
  f32x4 accU[9][2] = {};

  const short* aB = xp + (size_t)(tile * NKB) * (AFRAG * 8);
  const short* gB = Pg + (size_t)((e * NB + nb) * NKB) * (WFRAG * 8);
  const short* uB = Pu + (size_t)((e * NB + nb) * NKB) * (WFRAG * 8);

  const int wuni = (tid & 192) * 16;  // wave-uniform byte offset

#define STAGE1(kb, buf)                                                       \
  {                                                                           \
    const short* a = aB + (size_t)(kb) * (AFRAG * 8);                         \
    const short* g = gB + (size_t)(kb) * (WFRAG * 8);                         \
    const short* u = uB + (size_t)(kb) * (WFRAG * 8);                         \
    char* la = (char*)&L[buf][0];                                             \
    char* lg = (char*)&L[buf][4608];                                          \
    char* lu = (char*)&L[buf][8704];                                          \
    gload16(a + tid * 8, la + wuni);                                          \
    gload16(a + (256 + tid) * 8, la + 4096 + wuni);                           \
    if (tid < 64) gload16(a + (512 + tid) * 8, la + 8192 + wuni);             \
    gload16(g + tid * 8, lg + wuni);                                          \
    gload16(g + (256 + tid) * 8, lg + 4096 + wuni);                           \
    gload16(u + tid * 8, lu + wuni);                                          \
    gload16(u + (256 + tid) * 8, lu + 4096 + wuni);                           \
  }

  STAGE1(0, 0);
  asm volatile("s_waitcnt vmcnt(0)" ::: "memory");
  __syncthreads();

  int buf = 0;
  for (int kb = 0; kb < NKB; ++kb) {
    if (kb < NKB - 1) STAGE1(kb + 1, buf ^ 1);
    const short* As = &L[buf][0];
    const short* Gs = &L[buf][4608];
    const short* Us = &L[buf][8704];
    bf16x8 af[9], bg[2], bu[2];
#pragma unroll
    for (int m = 0; m < 9; ++m)
      af[m] = *(const bf16x8*)(As + (lks * 144 + m * 16 + l15) * 8);
#pragma unroll
    for (int n = 0; n < 2; ++n) {
      const int c = wv * 32 + n * 16 + l15;
      bg[n] = *(const bf16x8*)(Gs + (lks * 128 + c) * 8);
      bu[n] = *(const bf16x8*)(Us + (lks * 128 + c) * 8);
    }
    __builtin_amdgcn_s_setprio(1);
#pragma unroll
    for (int m = 0; m < 9; ++m)
#pragma unroll
      for (int n = 0; n < 2; ++n) {
        accG[m][n] = __builtin_amdgcn_mfma_f32_16x16x32_bf16(
            af[m], bg[n], accG[m][n], 0, 0, 0);
        accU[m][n] = __builtin_amdgcn_mfma_f32_16x16x32_bf16(
            af[m], bu[n], accU[m][n], 0, 0, 0);
      }
    __builtin_amdgcn_s_setprio(0);
    if (kb < NKB - 1) {
      asm volatile("s_waitcnt vmcnt(0)" ::: "memory");
      __syncthreads();
    }
    buf ^= 1;
  }
#undef STAGE1

  // epilogue: silu(g)*u -> packed inter [tile][kb2][4 ks][144 r]
#pragma unroll
  for (int n = 0; n < 2; ++n) {
    const int C = nb * 128 + wv * 32 + n * 16 + l15;
    const int kb2 = C >> 5, ks2 = (C >> 3) & 3, kj = C & 7;
    short* ib = inter + (((size_t)tile * NKB + kb2) * AFRAG + ks2 * 144) * 8 + kj;
#pragma unroll
    for (int m = 0; m < 9; ++m)
#pragma unroll
      for (int j = 0; j < 4; ++j) {
        const int r = m * 16 + (lks << 2) + j;
        const float g = accG[m][n][j], u = accU[m][n][j];
        const float s = g / (1.0f + __expf(-g));
        ib[(size_t)r * 8] = f2bf(s * u);
      }
  }
}

// GEMM2: packed inter @ packed down -> scatter fp32 out. BM=144,BN=128,BK=32.
__global__ __launch_bounds__(256, 2) void gemm2_kernel(
    const short* __restrict__ inter, const short* __restrict__ Pd,
    const int* __restrict__ row2tok, float* __restrict__ out) {
  const int b0 = blockIdx.x;
  const int swz = (b0 & 7) * 64 + (b0 >> 3);
  const int tile = swz >> 4, nb = swz & 15;
  const int e = tile >> 3;

  __shared__ short L[2][8704];  // per buf: A 4608 | B 4096 shorts

  const int tid = threadIdx.x, lane = tid & 63, wv = tid >> 6;
  const int l15 = lane & 15, lks = lane >> 4;

  f32x4 acc[9][2] = {};

  const short* aB = inter + (size_t)(tile * NKB) * (AFRAG * 8);
  const short* dB = Pd + (size_t)((e * NB + nb) * NKB) * (WFRAG * 8);

  const int wuni = (tid & 192) * 16;

#define STAGE2(kb, buf)                                                       \
  {                                                                           \
    const short* a = aB + (size_t)(kb) * (AFRAG * 8);                         \
    const short* d = dB + (size_t)(kb) * (WFRAG * 8);                         \
    char* la = (char*)&L[buf][0];                                             \
    char* ld = (char*)&L[buf][4608];                                          \
    gload16(a + tid * 8, la + wuni);                                          \
    gload16(a + (256 + tid) * 8, la + 4096 + wuni);                           \
    if (tid < 64) gload16(a + (512 + tid) * 8, la + 8192 + wuni);             \
    gload16(d + tid * 8, ld + wuni);                                          \
    gload16(d + (256 + tid) * 8, ld + 4096 + wuni);                           \
  }

  STAGE2(0, 0);
  asm volatile("s_waitcnt vmcnt(0)" ::: "memory");
  __syncthreads();

  int buf = 0;
  for (int kb = 0; kb < NKB; ++kb) {
    if (kb < NKB - 1) STAGE2(kb + 1, buf ^ 1);
    const short* As = &L[buf][0];
    const short* Bs = &L[buf][4608];
    bf16x8 af[9], bd[2];
#pragma unroll
    for (int m = 0; m < 9; ++m)
      af[m] = *(const bf16x8*)(As + (lks * 144 + m * 16 + l15) * 8);
#pragma unroll
    for (int n = 0; n < 2; ++n)
      bd[n] = *(const bf16x8*)(Bs + (lks * 128 + wv * 32 + n * 16 + l15) * 8);
    __builtin_amdgcn_s_setprio(1);
#pragma unroll
    for (int m = 0; m < 9; ++m)
#pragma unroll
      for (int n = 0; n < 2; ++n)
        acc[m][n] = __builtin_amdgcn_mfma_f32_16x16x32_bf16(af[m], bd[n],
                                                            acc[m][n], 0, 0, 0);
    __builtin_amdgcn_s_setprio(0);
    if (kb < NKB - 1) {
      asm volatile("s_waitcnt vmcnt(0)" ::: "memory");
      __syncthreads();
    }
    buf ^= 1;
  }
#undef STAGE2

#pragma unroll
  for (int m = 0; m < 9; ++m)
#pragma unroll
    for (int j = 0; j < 4; ++j) {
      const int r = tile * BM + m * 16 + (lks << 2) + j;
      const int tok = row2tok[r];
      if (tok >= 0) {
        float* orow = out + (size_t)tok * H_DIM + nb * 128 + wv * 32 + l15;
#pragma unroll
        for (int n = 0; n < 2; ++n) orow[n * 16] = acc[m][n][j];
      }
    }
}

// ======================= FALLBACK (round-1 kernels) =======================

__global__ void gather_fb_kernel(const float* __restrict__ hidden,
                                 const int* __restrict__ row2tok,
                                 short* __restrict__ xperm) {
  const int r = blockIdx.x;
  const int tok = row2tok[r];
  const int tid = threadIdx.x;
  f32x4 a = {0.f, 0.f, 0.f, 0.f}, b = {0.f, 0.f, 0.f, 0.f};
  if (tok >= 0) {
    const f32x4* src = (const f32x4*)(hidden + (size_t)tok * H_DIM + 8 * tid);
    a = src[0];
    b = src[1];
  }
  bf16x8 v;
  v[0] = f2bf(a[0]); v[1] = f2bf(a[1]); v[2] = f2bf(a[2]); v[3] = f2bf(a[3]);
  v[4] = f2bf(b[0]); v[5] = f2bf(b[1]); v[6] = f2bf(b[2]); v[7] = f2bf(b[3]);
  *(bf16x8*)(xperm + (size_t)r * H_DIM + 8 * tid) = v;
}

__global__ __launch_bounds__(256, 2) void gemm1_fb_kernel(
    const short* __restrict__ xperm, const float* __restrict__ gateW,
    const float* __restrict__ upW, const int* __restrict__ meta,
    short* __restrict__ inter) {
  const int tm = blockIdx.x;
  if (tm >= meta[0]) return;
  const int e = meta[1 + tm];
  const int rowBase = tm * 128;
  const int colBase = blockIdx.y * 128;
  const float* gW = gateW + (size_t)e * H_DIM * EI_DIM;
  const float* uW = upW + (size_t)e * H_DIM * EI_DIM;

  __shared__ short As[128 * 64];
  __shared__ short Bg[128 * 64];
  __shared__ short Bu[128 * 64];

  const int tid = threadIdx.x;
  const int lane = tid & 63;
  const int wv = tid >> 6;
  const int wr = (wv >> 1) * 64;
  const int wc = (wv & 1) * 64;

  f32x4 accG[4][4] = {};
  f32x4 accU[4][4] = {};

  const int ar = tid >> 3;
  const int ak = (tid & 7) * 8;
  const int bn = (tid & 31) * 4;
  const int bk = (tid >> 5) * 4;

  for (int k0 = 0; k0 < H_DIM; k0 += 64) {
    bf16x8 av[4];
#pragma unroll
    for (int p = 0; p < 4; ++p) {
      int r = ar + p * 32;
      av[p] = *(const bf16x8*)(xperm + (size_t)(rowBase + r) * H_DIM + k0 + ak);
    }
    f32x4 gv[2][4], uv[2][4];
#pragma unroll
    for (int p = 0; p < 2; ++p) {
      int kk = k0 + bk + p * 32;
#pragma unroll
      for (int i = 0; i < 4; ++i) {
        gv[p][i] = *(const f32x4*)(gW + (size_t)(kk + i) * EI_DIM + colBase + bn);
        uv[p][i] = *(const f32x4*)(uW + (size_t)(kk + i) * EI_DIM + colBase + bn);
      }
    }
    __syncthreads();
#pragma unroll
    for (int p = 0; p < 4; ++p) {
      int r = ar + p * 32;
      int idx = (r * 64 + ak) ^ ((r & 7) << 3);
      *(bf16x8*)(As + idx) = av[p];
    }
#pragma unroll
    for (int p = 0; p < 2; ++p) {
      int kk = bk + p * 32;
#pragma unroll
      for (int j = 0; j < 4; ++j) {
        int rowp = bn + j;
        int idx = (rowp * 64 + kk) ^ ((rowp & 7) << 3);
        bf16x4 vg, vu;
        vg[0] = f2bf(gv[p][0][j]); vg[1] = f2bf(gv[p][1][j]);
        vg[2] = f2bf(gv[p][2][j]); vg[3] = f2bf(gv[p][3][j]);
        vu[0] = f2bf(uv[p][0][j]); vu[1] = f2bf(uv[p][1][j]);
        vu[2] = f2bf(uv[p][2][j]); vu[3] = f2bf(uv[p][3][j]);
        *(bf16x4*)(Bg + idx) = vg;
        *(bf16x4*)(Bu + idx) = vu;
      }
    }
    __syncthreads();
#pragma unroll
    for (int kk = 0; kk < 64; kk += 32) {
      const int kb = kk + ((lane >> 4) << 3);
      bf16x8 af[4], bgf[4], buf_[4];
#pragma unroll
      for (int m = 0; m < 4; ++m) {
        int r = wr + m * 16 + (lane & 15);
        af[m] = *(const bf16x8*)(As + ((r * 64 + kb) ^ ((r & 7) << 3)));
      }
#pragma unroll
      for (int n = 0; n < 4; ++n) {
        int c = wc + n * 16 + (lane & 15);
        int idx = (c * 64 + kb) ^ ((c & 7) << 3);
        bgf[n] = *(const bf16x8*)(Bg + idx);
        buf_[n] = *(const bf16x8*)(Bu + idx);
      }
#pragma unroll
      for (int m = 0; m < 4; ++m)
#pragma unroll
        for (int n = 0; n < 4; ++n) {
          accG[m][n] = __builtin_amdgcn_mfma_f32_16x16x32_bf16(
              af[m], bgf[n], accG[m][n], 0, 0, 0);
          accU[m][n] = __builtin_amdgcn_mfma_f32_16x16x32_bf16(
              af[m], buf_[n], accU[m][n], 0, 0, 0);
        }
    }
  }
#pragma unroll
  for (int m = 0; m < 4; ++m)
#pragma unroll
    for (int n = 0; n < 4; ++n) {
      int c = colBase + wc + n * 16 + (lane & 15);
#pragma unroll
      for (int j = 0; j < 4; ++j) {
        int r = rowBase + wr + m * 16 + ((lane >> 4) << 2) + j;
        float g = accG[m][n][j], u = accU[m][n][j];
        float s = g / (1.0f + __expf(-g));
        inter[(size_t)r * EI_DIM + c] = f2bf(s * u);
      }
    }
}

__global__ __launch_bounds__(256, 2) void gemm2_fb_kernel(
    const short* __restrict__ inter, const float* __restrict__ downW,
    const int* __restrict__ meta, const int* __restrict__ row2tok,
    float* __restrict__ out) {
  const int tm = blockIdx.x;
  if (tm >= meta[0]) return;
  const int e = meta[1 + tm];
  const int rowBase = tm * 128;
  const int colBase = blockIdx.y * 128;
  const float* dW = downW + (size_t)e * EI_DIM * H_DIM;

  __shared__ short As[128 * 64];
  __shared__ short Bs[128 * 64];

  const int tid = threadIdx.x;
  const int lane = tid & 63;
  const int wv = tid >> 6;
  const int wr = (wv >> 1) * 64;
  const int wc = (wv & 1) * 64;

  f32x4 acc[4][4] = {};

  const int ar = tid >> 3;
  const int ak = (tid & 7) * 8;
  const int bn = (tid & 31) * 4;
  const int bk = (tid >> 5) * 4;

  for (int k0 = 0; k0 < EI_DIM; k0 += 64) {
    bf16x8 av[4];
#pragma unroll
    for (int p = 0; p < 4; ++p) {
      int r = ar + p * 32;
      av[p] = *(const bf16x8*)(inter + (size_t)(rowBase + r) * EI_DIM + k0 + ak);
    }
    f32x4 dv[2][4];
#pragma unroll
    for (int p = 0; p < 2; ++p) {
      int kk = k0 + bk + p * 32;
#pragma unroll
      for (int i = 0; i < 4; ++i)
        dv[p][i] = *(const f32x4*)(dW + (size_t)(kk + i) * H_DIM + colBase + bn);
    }
    __syncthreads();
#pragma unroll
    for (int p = 0; p < 4; ++p) {
      int r = ar + p * 32;
      int idx = (r * 64 + ak) ^ ((r & 7) << 3);
      *(bf16x8*)(As + idx) = av[p];
    }
#pragma unroll
    for (int p = 0; p < 2; ++p) {
      int kk = bk + p * 32;
#pragma unroll
      for (int j = 0; j < 4; ++j) {
        int rowp = bn + j;
        int idx = (rowp * 64 + kk) ^ ((rowp & 7) << 3);
        bf16x4 vd;
        vd[0] = f2bf(dv[p][0][j]); vd[1] = f2bf(dv[p][1][j]);
        vd[2] = f2bf(dv[p][2][j]); vd[3] = f2bf(dv[p][3][j]);
        *(bf16x4*)(Bs + idx) = vd;
      }
    }
    __syncthreads();
#pragma unroll
    for (int kk = 0; kk < 64; kk += 32) {
      const int kb = kk + ((lane >> 4) << 3);
      bf16x8 af[4], bf_[4];
#pragma unroll
      for (int m = 0; m < 4; ++m) {
        int r = wr + m * 16 + (lane & 15);
        af[m] = *(const bf16x8*)(As + ((r * 64 + kb) ^ ((r & 7) << 3)));
      }
#pragma unroll
      for (int n = 0; n < 4; ++n) {
        int c = wc + n * 16 + (lane & 15);
        bf_[n] = *(const bf16x8*)(Bs + ((c * 64 + kb) ^ ((c & 7) << 3)));
      }
#pragma unroll
      for (int m = 0; m < 4; ++m)
#pragma unroll
        for (int n = 0; n < 4; ++n)
          acc[m][n] = __builtin_amdgcn_mfma_f32_16x16x32_bf16(
              af[m], bf_[n], acc[m][n], 0, 0, 0);
    }
  }
#pragma unroll
  for (int m = 0; m < 4; ++m)
#pragma unroll
    for (int j = 0; j < 4; ++j) {
      int r = rowBase + wr + m * 16 + ((lane >> 4) << 2) + j;
      int tok = row2tok[r];
      if (tok >= 0) {
        float* orow = out + (size_t)tok * H_DIM + colBase + wc + (lane & 15);
#pragma unroll
        for (int n = 0; n < 4; ++n) orow[n * 16] = acc[m][n][j];
      }
    }
}

// ======================= launch =======================

extern "C" void kernel_launch(void* const* d_in, const int* in_sizes, int n_in,
                              void* d_out, int out_size, void* d_ws,
                              size_t ws_size, hipStream_t stream) {
  const float* hidden = (const float*)d_in[0];
  const void* token_ids = d_in[1];
  const float* gateW = (const float*)d_in[2];
  const float* upW = (const float*)d_in[3];
  const float* downW = (const float*)d_in[4];
  float* out = (float*)d_out;

  int* meta = (int*)d_ws;
  int* row2tok = meta + 64;

  const size_t wMatShorts = (size_t)NEXP * NB * 32 * 8192;       // 16.78M
  const size_t xpShorts = (size_t)NTM * NKB * AFRAG * 8;         // 9.44M
  const size_t need = 32768 + 3 * wMatShorts * 2 + 2 * xpShorts * 2;

  route_kernel<<<1, 256, 0, stream>>>(token_ids, meta, row2tok);

  if (ws_size >= need) {
    short* Pg = (short*)((char*)d_ws + 32768);
    short* Pu = Pg + wMatShorts;
    short* Pd = Pu + wMatShorts;
    short* xp = Pd + wMatShorts;
    short* inter = xp + xpShorts;

    convert_kernel<<<dim3(2048, 3), 256, 0, stream>>>(gateW, upW, downW, Pg,
                                                      Pu, Pd);
    gather_pack_kernel<<<dim3(NTM, NKB), 256, 0, stream>>>(hidden, row2tok, xp);
    gemm1_kernel<<<512, 256, 0, stream>>>(xp, Pg, Pu, inter);
    gemm2_kernel<<<512, 256, 0, stream>>>(inter, Pd, row2tok, out);
  } else {
    short* xperm = (short*)((char*)d_ws + 32768);
    short* inter = xperm + (size_t)NROWS * H_DIM;

    gather_fb_kernel<<<NROWS, 256, 0, stream>>>(hidden, row2tok, xperm);
    gemm1_fb_kernel<<<dim3(36, EI_DIM / 128), 256, 0, stream>>>(
        xperm, gateW, upW, meta, inter);
    gemm2_fb_kernel<<<dim3(36, H_DIM / 128), 256, 0, stream>>>(
        inter, downW, meta, row2tok, out);
  }
}

// Round 4
// 192.696 us; speedup vs baseline: 2.5945x; 1.0032x over previous
//
#include <hip/hip_runtime.h>

#define H_DIM 2048
#define EI_DIM 2048
#define NEXP 4
#define BM 144
#define SEG 1152           // rows per expert segment (8 tiles of 144)
#define NROWS 4608         // 4 * 1152 = 32 * 144
#define NTM 32             // row tiles of 144
#define NKB 64             // K blocks of 32
#define NB 16              // 128-col blocks per 2048
#define AFRAG 576          // frags per A k-tile (4 ks * 144 r)
#define WFRAG 512          // frags per weight k-tile (4 ks * 128 c)

typedef __attribute__((ext_vector_type(4))) float f32x4;
typedef __attribute__((ext_vector_type(8))) short bf16x8;
typedef __attribute__((ext_vector_type(4))) short bf16x4;

__device__ __forceinline__ short f2bf(float f) {
  unsigned u = __builtin_bit_cast(unsigned, f);
  u += 0x7fffu + ((u >> 16) & 1u);
  return (short)(u >> 16);
}

__device__ __forceinline__ void gload16(const void* g, void* l) {
  __builtin_amdgcn_global_load_lds(
      (const __attribute__((address_space(1))) unsigned*)g,
      (__attribute__((address_space(3))) unsigned*)l, 16, 0, 0);
}

// ---------------- routing: deterministic expert bucketing ----------------
__global__ void route_kernel(const void* __restrict__ token_ids,
                             int* __restrict__ meta, int* __restrict__ row2tok) {
  __shared__ unsigned long long wtot[4];
  const int tid = threadIdx.x;
  const int lane = tid & 63;
  const int wv = tid >> 6;

  for (int i = tid; i < NROWS; i += 256) row2tok[i] = -1;

  const int* ti32 = (const int*)token_ids;
  bool is64 = true;
  for (int i = 0; i < 16; ++i)
    if (ti32[2 * i + 1] != 0) is64 = false;

  const int base = tid * 16;
  unsigned long long pack = 0ULL;
  unsigned eps = 0;
  for (int i = 0; i < 16; ++i) {
    long long v = is64 ? ((const long long*)token_ids)[base + i]
                       : (long long)ti32[base + i];
    if (v < 0) v = 0;
    if (v > 99999) v = 99999;
    int e = (int)(v & 3);
    eps |= (unsigned)e << (2 * i);
    pack += 1ULL << (16 * e);
  }

  unsigned long long incl = pack;
  for (int off = 1; off < 64; off <<= 1) {
    unsigned long long up = __shfl_up(incl, off, 64);
    if (lane >= off) incl += up;
  }
  if (lane == 63) wtot[wv] = incl;
  __syncthreads();

  unsigned long long waveBase = 0;
  for (int w = 0; w < 4; ++w)
    if (w < wv) waveBase += wtot[w];
  const unsigned long long exclu = waveBase + incl - pack;

  if (tid == 0) {
    meta[0] = 36;
    for (int t = 0; t < 36; ++t) meta[1 + t] = t / 9;
  }

  int cur[4];
  for (int e = 0; e < 4; ++e)
    cur[e] = e * SEG + (int)((exclu >> (16 * e)) & 0xffff);
  for (int i = 0; i < 16; ++i) {
    int e = (int)((eps >> (2 * i)) & 3);
    int idx = cur[e]++;
    if (idx < (e + 1) * SEG) row2tok[idx] = base + i;
  }
}

// ======================= FAST PATH (packed layouts) =======================

// fp32 weights -> bf16 fragment-linear 16KB tiles.
// Grid decode: nb FASTEST so co-resident blocks read interleaved adjacent
// 512B columns of the same rows (contiguous aggregate stream).
__global__ __launch_bounds__(256) void convert_kernel(
    const float* __restrict__ gW, const float* __restrict__ uW,
    const float* __restrict__ dW, short* __restrict__ Pg,
    short* __restrict__ Pu, short* __restrict__ Pd) {
  const int mat = blockIdx.y;
  const float* src = mat == 0 ? gW : (mat == 1 ? uW : dW);
  short* dst = mat == 0 ? Pg : (mat == 1 ? Pu : Pd);
  const int tId = blockIdx.x;
  const int e = tId >> 9;
  const int kb = (tId >> 4) & 31;   // middle
  const int nb = tId & 15;          // fastest
  const int tid = threadIdx.x;
  const int ks = tid >> 5;          // 0..7
  const int c4 = (tid & 31) * 4;    // col group
  const float* sb = src + (size_t)e * H_DIM * EI_DIM +
                    (size_t)(kb * 64 + ks * 8) * 2048 + nb * 128 + c4;
  f32x4 rv[8];
#pragma unroll
  for (int j = 0; j < 8; ++j) rv[j] = *(const f32x4*)(sb + (size_t)j * 2048);
  short* db = dst + (size_t)(e * 512 + nb * 32 + kb) * 8192 + (ks * 128 + c4) * 8;
#pragma unroll
  for (int i = 0; i < 4; ++i) {
    bf16x8 v;
#pragma unroll
    for (int j = 0; j < 8; ++j) v[j] = f2bf(rv[j][i]);
    *(bf16x8*)(db + i * 8) = v;
  }
}

// gather permuted X rows -> [tile][kb32][4 ks][144 r] bf16 frags
__global__ __launch_bounds__(256) void gather_pack_kernel(
    const float* __restrict__ hidden, const int* __restrict__ row2tok,
    short* __restrict__ xp) {
  const int tile = blockIdx.x;   // 0..31
  const int kb = blockIdx.y;     // 0..63
  const int tid = threadIdx.x;
  short* db = xp + ((size_t)tile * NKB + kb) * (AFRAG * 8);
#pragma unroll
  for (int q = 0; q < 3; ++q) {
    if (q == 2 && tid >= 64) break;
    const int idx = q * 256 + tid;          // 0..575
    const int ks = idx / 144, r = idx - ks * 144;
    const int tok = row2tok[tile * BM + r];
    bf16x8 v = {0, 0, 0, 0, 0, 0, 0, 0};
    if (tok >= 0) {
      const f32x4* s =
          (const f32x4*)(hidden + (size_t)tok * H_DIM + kb * 32 + ks * 8);
      f32x4 a = s[0], b = s[1];
      v[0] = f2bf(a[0]); v[1] = f2bf(a[1]); v[2] = f2bf(a[2]); v[3] = f2bf(a[3]);
      v[4] = f2bf(b[0]); v[5] = f2bf(b[1]); v[6] = f2bf(b[2]); v[7] = f2bf(b[3]);
    }
    *(bf16x8*)(db + idx * 8) = v;
  }
}

// GEMM1: fused gate/up + SwiGLU. BM=144, BN=128 (G&U), BK=32.
// 3-deep pipeline, counted vmcnt (7 loads/wave/stage), one s_barrier/iter.
__global__ __launch_bounds__(256, 2) void gemm1_kernel(
    const short* __restrict__ xp, const short* __restrict__ Pg,
    const short* __restrict__ Pu, short* __restrict__ inter) {
  const int b0 = blockIdx.x;
  const int swz = (b0 & 7) * 64 + (b0 >> 3);  // 512 blocks, bijective
  const int tile = swz >> 4, nb = swz & 15;
  const int e = tile >> 3;

  __shared__ short L[3][12800];  // per buf: A 4608 | G 4096 | U 4096 shorts

  const int tid = threadIdx.x, lane = tid & 63, wv = tid >> 6;
  const int l15 = lane & 15, lks = lane >> 4;
  const int wuni = (tid & 192) * 16;  // wave-uniform byte offset

  f32x4 accG[9][2] = {};
  f32x4 accU[9][2] = {};

  const short* aB = xp + (size_t)(tile * NKB) * (AFRAG * 8);
  const short* gB = Pg + (size_t)((e * NB + nb) * NKB) * (WFRAG * 8);
  const short* uB = Pu + (size_t)((e * NB + nb) * NKB) * (WFRAG * 8);

  // 7 global_load_lds per wave per stage (uniform across waves)
#define STAGE1(kb, bf)                                                        \
  {                                                                           \
    const short* a = aB + (size_t)(kb) * (AFRAG * 8);                         \
    const short* g = gB + (size_t)(kb) * (WFRAG * 8);                         \
    const short* u = uB + (size_t)(kb) * (WFRAG * 8);                         \
    char* la = (char*)&L[bf][0];                                              \
    char* lg = (char*)&L[bf][4608];                                           \
    char* lu = (char*)&L[bf][8704];                                           \
    gload16(a + tid * 8, la + wuni);                                          \
    gload16(a + (256 + tid) * 8, la + 4096 + wuni);                           \
    if (lane < 16)                                                            \
      gload16(a + (512 + wv * 16 + lane) * 8, la + 8192 + wv * 256);          \
    gload16(g + tid * 8, lg + wuni);                                          \
    gload16(g + (256 + tid) * 8, lg + 4096 + wuni);                           \
    gload16(u + tid * 8, lu + wuni);                                          \
    gload16(u + (256 + tid) * 8, lu + 4096 + wuni);                           \
  }

  STAGE1(0, 0);
  STAGE1(1, 1);

  int bcur = 0;
  for (int kb = 0; kb < NKB; ++kb) {
    if (kb < NKB - 1)
      asm volatile("s_waitcnt vmcnt(7)" ::: "memory");
    else
      asm volatile("s_waitcnt vmcnt(0)" ::: "memory");
    __builtin_amdgcn_s_barrier();
    __builtin_amdgcn_sched_barrier(0);
    if (kb < NKB - 2) {
      int bn2 = bcur + 2;
      if (bn2 >= 3) bn2 -= 3;
      STAGE1(kb + 2, bn2);
    }
    const short* As = &L[bcur][0];
    const short* Gs = &L[bcur][4608];
    const short* Us = &L[bcur][8704];
    bf16x8 af[9], bg[2], bu[2];
#pragma unroll
    for (int m = 0; m < 9; ++m)
      af[m] = *(const bf16x8*)(As + (lks * 144 + m * 16 + l15) * 8);
#pragma unroll
    for (int n = 0; n < 2; ++n) {
      const int c = wv * 32 + n * 16 + l15;
      bg[n] = *(const bf16x8*)(Gs + (lks * 128 + c) * 8);
      bu[n] = *(const bf16x8*)(Us + (lks * 128 + c) * 8);
    }
    __builtin_amdgcn_s_setprio(1);
#pragma unroll
    for (int m = 0; m < 9; ++m)
#pragma unroll
      for (int n = 0; n < 2; ++n) {
        accG[m][n] = __builtin_amdgcn_mfma_f32_16x16x32_bf16(
            af[m], bg[n], accG[m][n], 0, 0, 0);
        accU[m][n] = __builtin_amdgcn_mfma_f32_16x16x32_bf16(
            af[m], bu[n], accU[m][n], 0, 0, 0);
      }
    __builtin_amdgcn_s_setprio(0);
    if (++bcur == 3) bcur = 0;
  }
#undef STAGE1

  // epilogue: silu(g)*u -> packed inter [tile][kb2][4 ks][144 r]
#pragma unroll
  for (int n = 0; n < 2; ++n) {
    const int C = nb * 128 + wv * 32 + n * 16 + l15;
    const int kb2 = C >> 5, ks2 = (C >> 3) & 3, kj = C & 7;
    short* ib = inter + (((size_t)tile * NKB + kb2) * AFRAG + ks2 * 144) * 8 + kj;
#pragma unroll
    for (int m = 0; m < 9; ++m)
#pragma unroll
      for (int j = 0; j < 4; ++j) {
        const int r = m * 16 + (lks << 2) + j;
        const float g = accG[m][n][j], u = accU[m][n][j];
        const float s = g / (1.0f + __expf(-g));
        ib[(size_t)r * 8] = f2bf(s * u);
      }
  }
}

// GEMM2: packed inter @ packed down -> scatter fp32 out. BM=144,BN=128,BK=32.
// 3-deep pipeline, counted vmcnt (5 loads/wave/stage).
__global__ __launch_bounds__(256, 2) void gemm2_kernel(
    const short* __restrict__ inter, const short* __restrict__ Pd,
    const int* __restrict__ row2tok, float* __restrict__ out) {
  const int b0 = blockIdx.x;
  const int swz = (b0 & 7) * 64 + (b0 >> 3);
  const int tile = swz >> 4, nb = swz & 15;
  const int e = tile >> 3;

  __shared__ short L[3][8704];  // per buf: A 4608 | B 4096 shorts

  const int tid = threadIdx.x, lane = tid & 63, wv = tid >> 6;
  const int l15 = lane & 15, lks = lane >> 4;
  const int wuni = (tid & 192) * 16;

  f32x4 acc[9][2] = {};

  const short* aB = inter + (size_t)(tile * NKB) * (AFRAG * 8);
  const short* dB = Pd + (size_t)((e * NB + nb) * NKB) * (WFRAG * 8);

#define STAGE2(kb, bf)                                                        \
  {                                                                           \
    const short* a = aB + (size_t)(kb) * (AFRAG * 8);                         \
    const short* d = dB + (size_t)(kb) * (WFRAG * 8);                         \
    char* la = (char*)&L[bf][0];                                              \
    char* ld = (char*)&L[bf][4608];                                           \
    gload16(a + tid * 8, la + wuni);                                          \
    gload16(a + (256 + tid) * 8, la + 4096 + wuni);                           \
    if (lane < 16)                                                            \
      gload16(a + (512 + wv * 16 + lane) * 8, la + 8192 + wv * 256);          \
    gload16(d + tid * 8, ld + wuni);                                          \
    gload16(d + (256 + tid) * 8, ld + 4096 + wuni);                           \
  }

  STAGE2(0, 0);
  STAGE2(1, 1);

  int bcur = 0;
  for (int kb = 0; kb < NKB; ++kb) {
    if (kb < NKB - 1)
      asm volatile("s_waitcnt vmcnt(5)" ::: "memory");
    else
      asm volatile("s_waitcnt vmcnt(0)" ::: "memory");
    __builtin_amdgcn_s_barrier();
    __builtin_amdgcn_sched_barrier(0);
    if (kb < NKB - 2) {
      int bn2 = bcur + 2;
      if (bn2 >= 3) bn2 -= 3;
      STAGE2(kb + 2, bn2);
    }
    const short* As = &L[bcur][0];
    const short* Bs = &L[bcur][4608];
    bf16x8 af[9], bd[2];
#pragma unroll
    for (int m = 0; m < 9; ++m)
      af[m] = *(const bf16x8*)(As + (lks * 144 + m * 16 + l15) * 8);
#pragma unroll
    for (int n = 0; n < 2; ++n)
      bd[n] = *(const bf16x8*)(Bs + (lks * 128 + wv * 32 + n * 16 + l15) * 8);
    __builtin_amdgcn_s_setprio(1);
#pragma unroll
    for (int m = 0; m < 9; ++m)
#pragma unroll
      for (int n = 0; n < 2; ++n)
        acc[m][n] = __builtin_amdgcn_mfma_f32_16x16x32_bf16(af[m], bd[n],
                                                            acc[m][n], 0, 0, 0);
    __builtin_amdgcn_s_setprio(0);
    if (++bcur == 3) bcur = 0;
  }
#undef STAGE2

#pragma unroll
  for (int m = 0; m < 9; ++m)
#pragma unroll
    for (int j = 0; j < 4; ++j) {
      const int r = tile * BM + m * 16 + (lks << 2) + j;
      const int tok = row2tok[r];
      if (tok >= 0) {
        float* orow = out + (size_t)tok * H_DIM + nb * 128 + wv * 32 + l15;
#pragma unroll
        for (int n = 0; n < 2; ++n) orow[n * 16] = acc[m][n][j];
      }
    }
}

// ======================= FALLBACK (round-1 kernels) =======================

__global__ void gather_fb_kernel(const float* __restrict__ hidden,
                                 const int* __restrict__ row2tok,
                                 short* __restrict__ xperm) {
  const int r = blockIdx.x;
  const int tok = row2tok[r];
  const int tid = threadIdx.x;
  f32x4 a = {0.f, 0.f, 0.f, 0.f}, b = {0.f, 0.f, 0.f, 0.f};
  if (tok >= 0) {
    const f32x4* src = (const f32x4*)(hidden + (size_t)tok * H_DIM + 8 * tid);
    a = src[0];
    b = src[1];
  }
  bf16x8 v;
  v[0] = f2bf(a[0]); v[1] = f2bf(a[1]); v[2] = f2bf(a[2]); v[3] = f2bf(a[3]);
  v[4] = f2bf(b[0]); v[5] = f2bf(b[1]); v[6] = f2bf(b[2]); v[7] = f2bf(b[3]);
  *(bf16x8*)(xperm + (size_t)r * H_DIM + 8 * tid) = v;
}

__global__ __launch_bounds__(256, 2) void gemm1_fb_kernel(
    const short* __restrict__ xperm, const float* __restrict__ gateW,
    const float* __restrict__ upW, const int* __restrict__ meta,
    short* __restrict__ inter) {
  const int tm = blockIdx.x;
  if (tm >= meta[0]) return;
  const int e = meta[1 + tm];
  const int rowBase = tm * 128;
  const int colBase = blockIdx.y * 128;
  const float* gW = gateW + (size_t)e * H_DIM * EI_DIM;
  const float* uW = upW + (size_t)e * H_DIM * EI_DIM;

  __shared__ short As[128 * 64];
  __shared__ short Bg[128 * 64];
  __shared__ short Bu[128 * 64];

  const int tid = threadIdx.x;
  const int lane = tid & 63;
  const int wv = tid >> 6;
  const int wr = (wv >> 1) * 64;
  const int wc = (wv & 1) * 64;

  f32x4 accG[4][4] = {};
  f32x4 accU[4][4] = {};

  const int ar = tid >> 3;
  const int ak = (tid & 7) * 8;
  const int bn = (tid & 31) * 4;
  const int bk = (tid >> 5) * 4;

  for (int k0 = 0; k0 < H_DIM; k0 += 64) {
    bf16x8 av[4];
#pragma unroll
    for (int p = 0; p < 4; ++p) {
      int r = ar + p * 32;
      av[p] = *(const bf16x8*)(xperm + (size_t)(rowBase + r) * H_DIM + k0 + ak);
    }
    f32x4 gv[2][4], uv[2][4];
#pragma unroll
    for (int p = 0; p < 2; ++p) {
      int kk = k0 + bk + p * 32;
#pragma unroll
      for (int i = 0; i < 4; ++i) {
        gv[p][i] = *(const f32x4*)(gW + (size_t)(kk + i) * EI_DIM + colBase + bn);
        uv[p][i] = *(const f32x4*)(uW + (size_t)(kk + i) * EI_DIM + colBase + bn);
      }
    }
    __syncthreads();
#pragma unroll
    for (int p = 0; p < 4; ++p) {
      int r = ar + p * 32;
      int idx = (r * 64 + ak) ^ ((r & 7) << 3);
      *(bf16x8*)(As + idx) = av[p];
    }
#pragma unroll
    for (int p = 0; p < 2; ++p) {
      int kk = bk + p * 32;
#pragma unroll
      for (int j = 0; j < 4; ++j) {
        int rowp = bn + j;
        int idx = (rowp * 64 + kk) ^ ((rowp & 7) << 3);
        bf16x4 vg, vu;
        vg[0] = f2bf(gv[p][0][j]); vg[1] = f2bf(gv[p][1][j]);
        vg[2] = f2bf(gv[p][2][j]); vg[3] = f2bf(gv[p][3][j]);
        vu[0] = f2bf(uv[p][0][j]); vu[1] = f2bf(uv[p][1][j]);
        vu[2] = f2bf(uv[p][2][j]); vu[3] = f2bf(uv[p][3][j]);
        *(bf16x4*)(Bg + idx) = vg;
        *(bf16x4*)(Bu + idx) = vu;
      }
    }
    __syncthreads();
#pragma unroll
    for (int kk = 0; kk < 64; kk += 32) {
      const int kb = kk + ((lane >> 4) << 3);
      bf16x8 af[4], bgf[4], buf_[4];
#pragma unroll
      for (int m = 0; m < 4; ++m) {
        int r = wr + m * 16 + (lane & 15);
        af[m] = *(const bf16x8*)(As + ((r * 64 + kb) ^ ((r & 7) << 3)));
      }
#pragma unroll
      for (int n = 0; n < 4; ++n) {
        int c = wc + n * 16 + (lane & 15);
        int idx = (c * 64 + kb) ^ ((c & 7) << 3);
        bgf[n] = *(const bf16x8*)(Bg + idx);
        buf_[n] = *(const bf16x8*)(Bu + idx);
      }
#pragma unroll
      for (int m = 0; m < 4; ++m)
#pragma unroll
        for (int n = 0; n < 4; ++n) {
          accG[m][n] = __builtin_amdgcn_mfma_f32_16x16x32_bf16(
              af[m], bgf[n], accG[m][n], 0, 0, 0);
          accU[m][n] = __builtin_amdgcn_mfma_f32_16x16x32_bf16(
              af[m], buf_[n], accU[m][n], 0, 0, 0);
        }
    }
  }
#pragma unroll
  for (int m = 0; m < 4; ++m)
#pragma unroll
    for (int n = 0; n < 4; ++n) {
      int c = colBase + wc + n * 16 + (lane & 15);
#pragma unroll
      for (int j = 0; j < 4; ++j) {
        int r = rowBase + wr + m * 16 + ((lane >> 4) << 2) + j;
        float g = accG[m][n][j], u = accU[m][n][j];
        float s = g / (1.0f + __expf(-g));
        inter[(size_t)r * EI_DIM + c] = f2bf(s * u);
      }
    }
}

__global__ __launch_bounds__(256, 2) void gemm2_fb_kernel(
    const short* __restrict__ inter, const float* __restrict__ downW,
    const int* __restrict__ meta, const int* __restrict__ row2tok,
    float* __restrict__ out) {
  const int tm = blockIdx.x;
  if (tm >= meta[0]) return;
  const int e = meta[1 + tm];
  const int rowBase = tm * 128;
  const int colBase = blockIdx.y * 128;
  const float* dW = downW + (size_t)e * EI_DIM * H_DIM;

  __shared__ short As[128 * 64];
  __shared__ short Bs[128 * 64];

  const int tid = threadIdx.x;
  const int lane = tid & 63;
  const int wv = tid >> 6;
  const int wr = (wv >> 1) * 64;
  const int wc = (wv & 1) * 64;

  f32x4 acc[4][4] = {};

  const int ar = tid >> 3;
  const int ak = (tid & 7) * 8;
  const int bn = (tid & 31) * 4;
  const int bk = (tid >> 5) * 4;

  for (int k0 = 0; k0 < EI_DIM; k0 += 64) {
    bf16x8 av[4];
#pragma unroll
    for (int p = 0; p < 4; ++p) {
      int r = ar + p * 32;
      av[p] = *(const bf16x8*)(inter + (size_t)(rowBase + r) * EI_DIM + k0 + ak);
    }
    f32x4 dv[2][4];
#pragma unroll
    for (int p = 0; p < 2; ++p) {
      int kk = k0 + bk + p * 32;
#pragma unroll
      for (int i = 0; i < 4; ++i)
        dv[p][i] = *(const f32x4*)(dW + (size_t)(kk + i) * H_DIM + colBase + bn);
    }
    __syncthreads();
#pragma unroll
    for (int p = 0; p < 4; ++p) {
      int r = ar + p * 32;
      int idx = (r * 64 + ak) ^ ((r & 7) << 3);
      *(bf16x8*)(As + idx) = av[p];
    }
#pragma unroll
    for (int p = 0; p < 2; ++p) {
      int kk = bk + p * 32;
#pragma unroll
      for (int j = 0; j < 4; ++j) {
        int rowp = bn + j;
        int idx = (rowp * 64 + kk) ^ ((rowp & 7) << 3);
        bf16x4 vd;
        vd[0] = f2bf(dv[p][0][j]); vd[1] = f2bf(dv[p][1][j]);
        vd[2] = f2bf(dv[p][2][j]); vd[3] = f2bf(dv[p][3][j]);
        *(bf16x4*)(Bs + idx) = vd;
      }
    }
    __syncthreads();
#pragma unroll
    for (int kk = 0; kk < 64; kk += 32) {
      const int kb = kk + ((lane >> 4) << 3);
      bf16x8 af[4], bf_[4];
#pragma unroll
      for (int m = 0; m < 4; ++m) {
        int r = wr + m * 16 + (lane & 15);
        af[m] = *(const bf16x8*)(As + ((r * 64 + kb) ^ ((r & 7) << 3)));
      }
#pragma unroll
      for (int n = 0; n < 4; ++n) {
        int c = wc + n * 16 + (lane & 15);
        bf_[n] = *(const bf16x8*)(Bs + ((c * 64 + kb) ^ ((c & 7) << 3)));
      }
#pragma unroll
      for (int m = 0; m < 4; ++m)
#pragma unroll
        for (int n = 0; n < 4; ++n)
          acc[m][n] = __builtin_amdgcn_mfma_f32_16x16x32_bf16(
              af[m], bf_[n], acc[m][n], 0, 0, 0);
    }
  }
#pragma unroll
  for (int m = 0; m < 4; ++m)
#pragma unroll
    for (int j = 0; j < 4; ++j) {
      int r = rowBase + wr + m * 16 + ((lane >> 4) << 2) + j;
      int tok = row2tok[r];
      if (tok >= 0) {
        float* orow = out + (size_t)tok * H_DIM + colBase + wc + (lane & 15);
#pragma unroll
        for (int n = 0; n < 4; ++n) orow[n * 16] = acc[m][n][j];
      }
    }
}

// ======================= launch =======================

extern "C" void kernel_launch(void* const* d_in, const int* in_sizes, int n_in,
                              void* d_out, int out_size, void* d_ws,
                              size_t ws_size, hipStream_t stream) {
  const float* hidden = (const float*)d_in[0];
  const void* token_ids = d_in[1];
  const float* gateW = (const float*)d_in[2];
  const float* upW = (const float*)d_in[3];
  const float* downW = (const float*)d_in[4];
  float* out = (float*)d_out;

  int* meta = (int*)d_ws;
  int* row2tok = meta + 64;

  const size_t wMatShorts = (size_t)NEXP * NB * 32 * 8192;       // 16.78M
  const size_t xpShorts = (size_t)NTM * NKB * AFRAG * 8;         // 9.44M
  const size_t need = 32768 + 3 * wMatShorts * 2 + 2 * xpShorts * 2;

  route_kernel<<<1, 256, 0, stream>>>(token_ids, meta, row2tok);

  if (ws_size >= need) {
    short* Pg = (short*)((char*)d_ws + 32768);
    short* Pu = Pg + wMatShorts;
    short* Pd = Pu + wMatShorts;
    short* xp = Pd + wMatShorts;
    short* inter = xp + xpShorts;

    convert_kernel<<<dim3(2048, 3), 256, 0, stream>>>(gateW, upW, downW, Pg,
                                                      Pu, Pd);
    gather_pack_kernel<<<dim3(NTM, NKB), 256, 0, stream>>>(hidden, row2tok, xp);
    gemm1_kernel<<<512, 256, 0, stream>>>(xp, Pg, Pu, inter);
    gemm2_kernel<<<512, 256, 0, stream>>>(inter, Pd, row2tok, out);
  } else {
    short* xperm = (short*)((char*)d_ws + 32768);
    short* inter = xperm + (size_t)NROWS * H_DIM;

    gather_fb_kernel<<<NROWS, 256, 0, stream>>>(hidden, row2tok, xperm);
    gemm1_fb_kernel<<<dim3(36, EI_DIM / 128), 256, 0, stream>>>(
        xperm, gateW, upW, meta, inter);
    gemm2_fb_kernel<<<dim3(36, H_DIM / 128), 256, 0, stream>>>(
        inter, downW, meta, row2tok, out);
  }
}

// Round 5
// 180.025 us; speedup vs baseline: 2.7771x; 1.0704x over previous
//
#include <hip/hip_runtime.h>

#define H_DIM 2048
#define EI_DIM 2048
#define NEXP 4
#define BM 144
#define SEG 1152           // rows per expert segment (8 tiles of 144)
#define NROWS 4608         // 4 * 1152 = 32 * 144
#define NTM 32             // row tiles of 144
#define NKB 64             // K blocks of 32
#define NB 16              // 128-col blocks per 2048
#define AFRAG 576          // frags per A k-tile (4 ks * 144 r)
#define WFRAG 512          // frags per weight k-tile (4 ks * 128 c)

typedef __attribute__((ext_vector_type(4))) float f32x4;
typedef __attribute__((ext_vector_type(8))) short bf16x8;
typedef __attribute__((ext_vector_type(4))) short bf16x4;

__device__ __forceinline__ short f2bf(float f) {
  unsigned u = __builtin_bit_cast(unsigned, f);
  u += 0x7fffu + ((u >> 16) & 1u);
  return (short)(u >> 16);
}

__device__ __forceinline__ void gload16(const void* g, void* l) {
  __builtin_amdgcn_global_load_lds(
      (const __attribute__((address_space(1))) unsigned*)g,
      (__attribute__((address_space(3))) unsigned*)l, 16, 0, 0);
}

// ---------------- routing: deterministic expert bucketing ----------------
__global__ void route_kernel(const void* __restrict__ token_ids,
                             int* __restrict__ meta, int* __restrict__ row2tok) {
  __shared__ unsigned long long wtot[4];
  const int tid = threadIdx.x;
  const int lane = tid & 63;
  const int wv = tid >> 6;

  for (int i = tid; i < NROWS; i += 256) row2tok[i] = -1;

  const int* ti32 = (const int*)token_ids;
  bool is64 = true;
  for (int i = 0; i < 16; ++i)
    if (ti32[2 * i + 1] != 0) is64 = false;

  const int base = tid * 16;
  unsigned long long pack = 0ULL;
  unsigned eps = 0;
  for (int i = 0; i < 16; ++i) {
    long long v = is64 ? ((const long long*)token_ids)[base + i]
                       : (long long)ti32[base + i];
    if (v < 0) v = 0;
    if (v > 99999) v = 99999;
    int e = (int)(v & 3);
    eps |= (unsigned)e << (2 * i);
    pack += 1ULL << (16 * e);
  }

  unsigned long long incl = pack;
  for (int off = 1; off < 64; off <<= 1) {
    unsigned long long up = __shfl_up(incl, off, 64);
    if (lane >= off) incl += up;
  }
  if (lane == 63) wtot[wv] = incl;
  __syncthreads();

  unsigned long long waveBase = 0;
  for (int w = 0; w < 4; ++w)
    if (w < wv) waveBase += wtot[w];
  const unsigned long long exclu = waveBase + incl - pack;

  if (tid == 0) {
    meta[0] = 36;
    for (int t = 0; t < 36; ++t) meta[1 + t] = t / 9;
  }

  int cur[4];
  for (int e = 0; e < 4; ++e)
    cur[e] = e * SEG + (int)((exclu >> (16 * e)) & 0xffff);
  for (int i = 0; i < 16; ++i) {
    int e = (int)((eps >> (2 * i)) & 3);
    int idx = cur[e]++;
    if (idx < (e + 1) * SEG) row2tok[idx] = base + i;
  }
}

// ======================= FAST PATH (packed layouts) =======================

// Fused convert (roles 0..2) + gather (role 3).
// Convert: lane owns one column; loads 32x dword (256B/instr coalesced),
// stores 4x dwordx4 with 64 lanes x 16B = 1KB DENSE per store instruction.
__global__ __launch_bounds__(256) void convert_gather_kernel(
    const float* __restrict__ gW, const float* __restrict__ uW,
    const float* __restrict__ dW, const float* __restrict__ hidden,
    const int* __restrict__ row2tok, short* __restrict__ Pg,
    short* __restrict__ Pu, short* __restrict__ Pd, short* __restrict__ xp) {
  const int role = blockIdx.y;
  const int tid = threadIdx.x;

  if (role == 3) {
    // gather permuted X rows -> [tile][kb32][4 ks][144 r] bf16 frags
    const int tile = blockIdx.x >> 6;  // 0..31
    const int kb = blockIdx.x & 63;    // 0..63
    short* db = xp + ((size_t)tile * NKB + kb) * (AFRAG * 8);
#pragma unroll
    for (int q = 0; q < 3; ++q) {
      if (q == 2 && tid >= 64) break;
      const int idx = q * 256 + tid;  // 0..575
      const int ks = idx / 144, r = idx - ks * 144;
      const int tok = row2tok[tile * BM + r];
      bf16x8 v = {0, 0, 0, 0, 0, 0, 0, 0};
      if (tok >= 0) {
        const f32x4* s =
            (const f32x4*)(hidden + (size_t)tok * H_DIM + kb * 32 + ks * 8);
        f32x4 a = s[0], b = s[1];
        v[0] = f2bf(a[0]); v[1] = f2bf(a[1]); v[2] = f2bf(a[2]); v[3] = f2bf(a[3]);
        v[4] = f2bf(b[0]); v[5] = f2bf(b[1]); v[6] = f2bf(b[2]); v[7] = f2bf(b[3]);
      }
      *(bf16x8*)(db + idx * 8) = v;
    }
    return;
  }

  const float* src = role == 0 ? gW : (role == 1 ? uW : dW);
  short* dst = role == 0 ? Pg : (role == 1 ? Pu : Pd);
  const int tId = blockIdx.x;
  const int e = tId >> 9;
  const int kb = (tId >> 4) & 31;
  const int nb = tId & 15;
  const int c = tid & 127;   // column owned by this lane
  const int h = tid >> 7;    // ks half (0..1)
  const float* sb = src + (size_t)e * H_DIM * EI_DIM +
                    (size_t)(kb * 64 + h * 32) * 2048 + nb * 128 + c;
  short* db =
      dst + (size_t)(e * 512 + nb * 32 + kb) * 8192 + (size_t)(h * 512 + c) * 8;
#pragma unroll
  for (int ksp = 0; ksp < 4; ++ksp) {
    float rv[8];
#pragma unroll
    for (int j = 0; j < 8; ++j)
      rv[j] = sb[(size_t)(ksp * 8 + j) * 2048];
    bf16x8 v;
#pragma unroll
    for (int j = 0; j < 8; ++j) v[j] = f2bf(rv[j]);
    *(bf16x8*)(db + (size_t)ksp * 1024) = v;  // frag (h*4+ksp)*128 + c
  }
}

// GEMM1: fused gate/up + SwiGLU. BM=144, BN=128 (G&U), BK=32.
// 3-deep pipeline, counted vmcnt (7 loads/wave/stage), one s_barrier/iter.
__global__ __launch_bounds__(256, 2) void gemm1_kernel(
    const short* __restrict__ xp, const short* __restrict__ Pg,
    const short* __restrict__ Pu, short* __restrict__ inter) {
  const int b0 = blockIdx.x;
  const int swz = (b0 & 7) * 64 + (b0 >> 3);  // 512 blocks, bijective
  const int tile = swz >> 4, nb = swz & 15;
  const int e = tile >> 3;

  __shared__ short L[3][12800];  // per buf: A 4608 | G 4096 | U 4096 shorts

  const int tid = threadIdx.x, lane = tid & 63, wv = tid >> 6;
  const int l15 = lane & 15, lks = lane >> 4;
  const int wuni = (tid & 192) * 16;  // wave-uniform byte offset

  f32x4 accG[9][2] = {};
  f32x4 accU[9][2] = {};

  const short* aB = xp + (size_t)(tile * NKB) * (AFRAG * 8);
  const short* gB = Pg + (size_t)((e * NB + nb) * NKB) * (WFRAG * 8);
  const short* uB = Pu + (size_t)((e * NB + nb) * NKB) * (WFRAG * 8);

  // 7 global_load_lds per wave per stage (uniform across waves)
#define STAGE1(kb, bf)                                                        \
  {                                                                           \
    const short* a = aB + (size_t)(kb) * (AFRAG * 8);                         \
    const short* g = gB + (size_t)(kb) * (WFRAG * 8);                         \
    const short* u = uB + (size_t)(kb) * (WFRAG * 8);                         \
    char* la = (char*)&L[bf][0];                                              \
    char* lg = (char*)&L[bf][4608];                                           \
    char* lu = (char*)&L[bf][8704];                                           \
    gload16(a + tid * 8, la + wuni);                                          \
    gload16(a + (256 + tid) * 8, la + 4096 + wuni);                           \
    if (lane < 16)                                                            \
      gload16(a + (512 + wv * 16 + lane) * 8, la + 8192 + wv * 256);          \
    gload16(g + tid * 8, lg + wuni);                                          \
    gload16(g + (256 + tid) * 8, lg + 4096 + wuni);                           \
    gload16(u + tid * 8, lu + wuni);                                          \
    gload16(u + (256 + tid) * 8, lu + 4096 + wuni);                           \
  }

  STAGE1(0, 0);
  STAGE1(1, 1);

  int bcur = 0;
  for (int kb = 0; kb < NKB; ++kb) {
    if (kb < NKB - 1)
      asm volatile("s_waitcnt vmcnt(7)" ::: "memory");
    else
      asm volatile("s_waitcnt vmcnt(0)" ::: "memory");
    __builtin_amdgcn_s_barrier();
    __builtin_amdgcn_sched_barrier(0);
    if (kb < NKB - 2) {
      int bn2 = bcur + 2;
      if (bn2 >= 3) bn2 -= 3;
      STAGE1(kb + 2, bn2);
    }
    const short* As = &L[bcur][0];
    const short* Gs = &L[bcur][4608];
    const short* Us = &L[bcur][8704];
    bf16x8 af[9], bg[2], bu[2];
#pragma unroll
    for (int m = 0; m < 9; ++m)
      af[m] = *(const bf16x8*)(As + (lks * 144 + m * 16 + l15) * 8);
#pragma unroll
    for (int n = 0; n < 2; ++n) {
      const int c = wv * 32 + n * 16 + l15;
      bg[n] = *(const bf16x8*)(Gs + (lks * 128 + c) * 8);
      bu[n] = *(const bf16x8*)(Us + (lks * 128 + c) * 8);
    }
    __builtin_amdgcn_s_setprio(1);
#pragma unroll
    for (int m = 0; m < 9; ++m)
#pragma unroll
      for (int n = 0; n < 2; ++n) {
        accG[m][n] = __builtin_amdgcn_mfma_f32_16x16x32_bf16(
            af[m], bg[n], accG[m][n], 0, 0, 0);
        accU[m][n] = __builtin_amdgcn_mfma_f32_16x16x32_bf16(
            af[m], bu[n], accU[m][n], 0, 0, 0);
      }
    __builtin_amdgcn_s_setprio(0);
    if (++bcur == 3) bcur = 0;
  }
#undef STAGE1

  // epilogue: silu(g)*u -> packed inter [tile][kb2][4 ks][144 r]
#pragma unroll
  for (int n = 0; n < 2; ++n) {
    const int C = nb * 128 + wv * 32 + n * 16 + l15;
    const int kb2 = C >> 5, ks2 = (C >> 3) & 3, kj = C & 7;
    short* ib = inter + (((size_t)tile * NKB + kb2) * AFRAG + ks2 * 144) * 8 + kj;
#pragma unroll
    for (int m = 0; m < 9; ++m)
#pragma unroll
      for (int j = 0; j < 4; ++j) {
        const int r = m * 16 + (lks << 2) + j;
        const float g = accG[m][n][j], u = accU[m][n][j];
        const float s = g / (1.0f + __expf(-g));
        ib[(size_t)r * 8] = f2bf(s * u);
      }
  }
}

// GEMM2: packed inter @ packed down -> scatter fp32 out. BM=144,BN=128,BK=32.
// 3-deep pipeline, counted vmcnt (5 loads/wave/stage).
__global__ __launch_bounds__(256, 2) void gemm2_kernel(
    const short* __restrict__ inter, const short* __restrict__ Pd,
    const int* __restrict__ row2tok, float* __restrict__ out) {
  const int b0 = blockIdx.x;
  const int swz = (b0 & 7) * 64 + (b0 >> 3);
  const int tile = swz >> 4, nb = swz & 15;
  const int e = tile >> 3;

  __shared__ short L[3][8704];  // per buf: A 4608 | B 4096 shorts

  const int tid = threadIdx.x, lane = tid & 63, wv = tid >> 6;
  const int l15 = lane & 15, lks = lane >> 4;
  const int wuni = (tid & 192) * 16;

  f32x4 acc[9][2] = {};

  const short* aB = inter + (size_t)(tile * NKB) * (AFRAG * 8);
  const short* dB = Pd + (size_t)((e * NB + nb) * NKB) * (WFRAG * 8);

#define STAGE2(kb, bf)                                                        \
  {                                                                           \
    const short* a = aB + (size_t)(kb) * (AFRAG * 8);                         \
    const short* d = dB + (size_t)(kb) * (WFRAG * 8);                         \
    char* la = (char*)&L[bf][0];                                              \
    char* ld = (char*)&L[bf][4608];                                           \
    gload16(a + tid * 8, la + wuni);                                          \
    gload16(a + (256 + tid) * 8, la + 4096 + wuni);                           \
    if (lane < 16)                                                            \
      gload16(a + (512 + wv * 16 + lane) * 8, la + 8192 + wv * 256);          \
    gload16(d + tid * 8, ld + wuni);                                          \
    gload16(d + (256 + tid) * 8, ld + 4096 + wuni);                           \
  }

  STAGE2(0, 0);
  STAGE2(1, 1);

  int bcur = 0;
  for (int kb = 0; kb < NKB; ++kb) {
    if (kb < NKB - 1)
      asm volatile("s_waitcnt vmcnt(5)" ::: "memory");
    else
      asm volatile("s_waitcnt vmcnt(0)" ::: "memory");
    __builtin_amdgcn_s_barrier();
    __builtin_amdgcn_sched_barrier(0);
    if (kb < NKB - 2) {
      int bn2 = bcur + 2;
      if (bn2 >= 3) bn2 -= 3;
      STAGE2(kb + 2, bn2);
    }
    const short* As = &L[bcur][0];
    const short* Bs = &L[bcur][4608];
    bf16x8 af[9], bd[2];
#pragma unroll
    for (int m = 0; m < 9; ++m)
      af[m] = *(const bf16x8*)(As + (lks * 144 + m * 16 + l15) * 8);
#pragma unroll
    for (int n = 0; n < 2; ++n)
      bd[n] = *(const bf16x8*)(Bs + (lks * 128 + wv * 32 + n * 16 + l15) * 8);
    __builtin_amdgcn_s_setprio(1);
#pragma unroll
    for (int m = 0; m < 9; ++m)
#pragma unroll
      for (int n = 0; n < 2; ++n)
        acc[m][n] = __builtin_amdgcn_mfma_f32_16x16x32_bf16(af[m], bd[n],
                                                            acc[m][n], 0, 0, 0);
    __builtin_amdgcn_s_setprio(0);
    if (++bcur == 3) bcur = 0;
  }
#undef STAGE2

#pragma unroll
  for (int m = 0; m < 9; ++m)
#pragma unroll
    for (int j = 0; j < 4; ++j) {
      const int r = tile * BM + m * 16 + (lks << 2) + j;
      const int tok = row2tok[r];
      if (tok >= 0) {
        float* orow = out + (size_t)tok * H_DIM + nb * 128 + wv * 32 + l15;
#pragma unroll
        for (int n = 0; n < 2; ++n) orow[n * 16] = acc[m][n][j];
      }
    }
}

// ======================= FALLBACK (round-1 kernels) =======================

__global__ void gather_fb_kernel(const float* __restrict__ hidden,
                                 const int* __restrict__ row2tok,
                                 short* __restrict__ xperm) {
  const int r = blockIdx.x;
  const int tok = row2tok[r];
  const int tid = threadIdx.x;
  f32x4 a = {0.f, 0.f, 0.f, 0.f}, b = {0.f, 0.f, 0.f, 0.f};
  if (tok >= 0) {
    const f32x4* src = (const f32x4*)(hidden + (size_t)tok * H_DIM + 8 * tid);
    a = src[0];
    b = src[1];
  }
  bf16x8 v;
  v[0] = f2bf(a[0]); v[1] = f2bf(a[1]); v[2] = f2bf(a[2]); v[3] = f2bf(a[3]);
  v[4] = f2bf(b[0]); v[5] = f2bf(b[1]); v[6] = f2bf(b[2]); v[7] = f2bf(b[3]);
  *(bf16x8*)(xperm + (size_t)r * H_DIM + 8 * tid) = v;
}

__global__ __launch_bounds__(256, 2) void gemm1_fb_kernel(
    const short* __restrict__ xperm, const float* __restrict__ gateW,
    const float* __restrict__ upW, const int* __restrict__ meta,
    short* __restrict__ inter) {
  const int tm = blockIdx.x;
  if (tm >= meta[0]) return;
  const int e = meta[1 + tm];
  const int rowBase = tm * 128;
  const int colBase = blockIdx.y * 128;
  const float* gW = gateW + (size_t)e * H_DIM * EI_DIM;
  const float* uW = upW + (size_t)e * H_DIM * EI_DIM;

  __shared__ short As[128 * 64];
  __shared__ short Bg[128 * 64];
  __shared__ short Bu[128 * 64];

  const int tid = threadIdx.x;
  const int lane = tid & 63;
  const int wv = tid >> 6;
  const int wr = (wv >> 1) * 64;
  const int wc = (wv & 1) * 64;

  f32x4 accG[4][4] = {};
  f32x4 accU[4][4] = {};

  const int ar = tid >> 3;
  const int ak = (tid & 7) * 8;
  const int bn = (tid & 31) * 4;
  const int bk = (tid >> 5) * 4;

  for (int k0 = 0; k0 < H_DIM; k0 += 64) {
    bf16x8 av[4];
#pragma unroll
    for (int p = 0; p < 4; ++p) {
      int r = ar + p * 32;
      av[p] = *(const bf16x8*)(xperm + (size_t)(rowBase + r) * H_DIM + k0 + ak);
    }
    f32x4 gv[2][4], uv[2][4];
#pragma unroll
    for (int p = 0; p < 2; ++p) {
      int kk = k0 + bk + p * 32;
#pragma unroll
      for (int i = 0; i < 4; ++i) {
        gv[p][i] = *(const f32x4*)(gW + (size_t)(kk + i) * EI_DIM + colBase + bn);
        uv[p][i] = *(const f32x4*)(uW + (size_t)(kk + i) * EI_DIM + colBase + bn);
      }
    }
    __syncthreads();
#pragma unroll
    for (int p = 0; p < 4; ++p) {
      int r = ar + p * 32;
      int idx = (r * 64 + ak) ^ ((r & 7) << 3);
      *(bf16x8*)(As + idx) = av[p];
    }
#pragma unroll
    for (int p = 0; p < 2; ++p) {
      int kk = bk + p * 32;
#pragma unroll
      for (int j = 0; j < 4; ++j) {
        int rowp = bn + j;
        int idx = (rowp * 64 + kk) ^ ((rowp & 7) << 3);
        bf16x4 vg, vu;
        vg[0] = f2bf(gv[p][0][j]); vg[1] = f2bf(gv[p][1][j]);
        vg[2] = f2bf(gv[p][2][j]); vg[3] = f2bf(gv[p][3][j]);
        vu[0] = f2bf(uv[p][0][j]); vu[1] = f2bf(uv[p][1][j]);
        vu[2] = f2bf(uv[p][2][j]); vu[3] = f2bf(uv[p][3][j]);
        *(bf16x4*)(Bg + idx) = vg;
        *(bf16x4*)(Bu + idx) = vu;
      }
    }
    __syncthreads();
#pragma unroll
    for (int kk = 0; kk < 64; kk += 32) {
      const int kb = kk + ((lane >> 4) << 3);
      bf16x8 af[4], bgf[4], buf_[4];
#pragma unroll
      for (int m = 0; m < 4; ++m) {
        int r = wr + m * 16 + (lane & 15);
        af[m] = *(const bf16x8*)(As + ((r * 64 + kb) ^ ((r & 7) << 3)));
      }
#pragma unroll
      for (int n = 0; n < 4; ++n) {
        int c = wc + n * 16 + (lane & 15);
        int idx = (c * 64 + kb) ^ ((c & 7) << 3);
        bgf[n] = *(const bf16x8*)(Bg + idx);
        buf_[n] = *(const bf16x8*)(Bu + idx);
      }
#pragma unroll
      for (int m = 0; m < 4; ++m)
#pragma unroll
        for (int n = 0; n < 4; ++n) {
          accG[m][n] = __builtin_amdgcn_mfma_f32_16x16x32_bf16(
              af[m], bgf[n], accG[m][n], 0, 0, 0);
          accU[m][n] = __builtin_amdgcn_mfma_f32_16x16x32_bf16(
              af[m], buf_[n], accU[m][n], 0, 0, 0);
        }
    }
  }
#pragma unroll
  for (int m = 0; m < 4; ++m)
#pragma unroll
    for (int n = 0; n < 4; ++n) {
      int c = colBase + wc + n * 16 + (lane & 15);
#pragma unroll
      for (int j = 0; j < 4; ++j) {
        int r = rowBase + wr + m * 16 + ((lane >> 4) << 2) + j;
        float g = accG[m][n][j], u = accU[m][n][j];
        float s = g / (1.0f + __expf(-g));
        inter[(size_t)r * EI_DIM + c] = f2bf(s * u);
      }
    }
}

__global__ __launch_bounds__(256, 2) void gemm2_fb_kernel(
    const short* __restrict__ inter, const float* __restrict__ downW,
    const int* __restrict__ meta, const int* __restrict__ row2tok,
    float* __restrict__ out) {
  const int tm = blockIdx.x;
  if (tm >= meta[0]) return;
  const int e = meta[1 + tm];
  const int rowBase = tm * 128;
  const int colBase = blockIdx.y * 128;
  const float* dW = downW + (size_t)e * EI_DIM * H_DIM;

  __shared__ short As[128 * 64];
  __shared__ short Bs[128 * 64];

  const int tid = threadIdx.x;
  const int lane = tid & 63;
  const int wv = tid >> 6;
  const int wr = (wv >> 1) * 64;
  const int wc = (wv & 1) * 64;

  f32x4 acc[4][4] = {};

  const int ar = tid >> 3;
  const int ak = (tid & 7) * 8;
  const int bn = (tid & 31) * 4;
  const int bk = (tid >> 5) * 4;

  for (int k0 = 0; k0 < EI_DIM; k0 += 64) {
    bf16x8 av[4];
#pragma unroll
    for (int p = 0; p < 4; ++p) {
      int r = ar + p * 32;
      av[p] = *(const bf16x8*)(inter + (size_t)(rowBase + r) * EI_DIM + k0 + ak);
    }
    f32x4 dv[2][4];
#pragma unroll
    for (int p = 0; p < 2; ++p) {
      int kk = k0 + bk + p * 32;
#pragma unroll
      for (int i = 0; i < 4; ++i)
        dv[p][i] = *(const f32x4*)(dW + (size_t)(kk + i) * H_DIM + colBase + bn);
    }
    __syncthreads();
#pragma unroll
    for (int p = 0; p < 4; ++p) {
      int r = ar + p * 32;
      int idx = (r * 64 + ak) ^ ((r & 7) << 3);
      *(bf16x8*)(As + idx) = av[p];
    }
#pragma unroll
    for (int p = 0; p < 2; ++p) {
      int kk = bk + p * 32;
#pragma unroll
      for (int j = 0; j < 4; ++j) {
        int rowp = bn + j;
        int idx = (rowp * 64 + kk) ^ ((rowp & 7) << 3);
        bf16x4 vd;
        vd[0] = f2bf(dv[p][0][j]); vd[1] = f2bf(dv[p][1][j]);
        vd[2] = f2bf(dv[p][2][j]); vd[3] = f2bf(dv[p][3][j]);
        *(bf16x4*)(Bs + idx) = vd;
      }
    }
    __syncthreads();
#pragma unroll
    for (int kk = 0; kk < 64; kk += 32) {
      const int kb = kk + ((lane >> 4) << 3);
      bf16x8 af[4], bf_[4];
#pragma unroll
      for (int m = 0; m < 4; ++m) {
        int r = wr + m * 16 + (lane & 15);
        af[m] = *(const bf16x8*)(As + ((r * 64 + kb) ^ ((r & 7) << 3)));
      }
#pragma unroll
      for (int n = 0; n < 4; ++n) {
        int c = wc + n * 16 + (lane & 15);
        bf_[n] = *(const bf16x8*)(Bs + ((c * 64 + kb) ^ ((c & 7) << 3)));
      }
#pragma unroll
      for (int m = 0; m < 4; ++m)
#pragma unroll
        for (int n = 0; n < 4; ++n)
          acc[m][n] = __builtin_amdgcn_mfma_f32_16x16x32_bf16(
              af[m], bf_[n], acc[m][n], 0, 0, 0);
    }
  }
#pragma unroll
  for (int m = 0; m < 4; ++m)
#pragma unroll
    for (int j = 0; j < 4; ++j) {
      int r = rowBase + wr + m * 16 + ((lane >> 4) << 2) + j;
      int tok = row2tok[r];
      if (tok >= 0) {
        float* orow = out + (size_t)tok * H_DIM + colBase + wc + (lane & 15);
#pragma unroll
        for (int n = 0; n < 4; ++n) orow[n * 16] = acc[m][n][j];
      }
    }
}

// ======================= launch =======================

extern "C" void kernel_launch(void* const* d_in, const int* in_sizes, int n_in,
                              void* d_out, int out_size, void* d_ws,
                              size_t ws_size, hipStream_t stream) {
  const float* hidden = (const float*)d_in[0];
  const void* token_ids = d_in[1];
  const float* gateW = (const float*)d_in[2];
  const float* upW = (const float*)d_in[3];
  const float* downW = (const float*)d_in[4];
  float* out = (float*)d_out;

  int* meta = (int*)d_ws;
  int* row2tok = meta + 64;

  const size_t wMatShorts = (size_t)NEXP * NB * 32 * 8192;       // 16.78M
  const size_t xpShorts = (size_t)NTM * NKB * AFRAG * 8;         // 9.44M
  const size_t need = 32768 + 3 * wMatShorts * 2 + 2 * xpShorts * 2;

  route_kernel<<<1, 256, 0, stream>>>(token_ids, meta, row2tok);

  if (ws_size >= need) {
    short* Pg = (short*)((char*)d_ws + 32768);
    short* Pu = Pg + wMatShorts;
    short* Pd = Pu + wMatShorts;
    short* xp = Pd + wMatShorts;
    short* inter = xp + xpShorts;

    convert_gather_kernel<<<dim3(2048, 4), 256, 0, stream>>>(
        gateW, upW, downW, hidden, row2tok, Pg, Pu, Pd, xp);
    gemm1_kernel<<<512, 256, 0, stream>>>(xp, Pg, Pu, inter);
    gemm2_kernel<<<512, 256, 0, stream>>>(inter, Pd, row2tok, out);
  } else {
    short* xperm = (short*)((char*)d_ws + 32768);
    short* inter = xperm + (size_t)NROWS * H_DIM;

    gather_fb_kernel<<<NROWS, 256, 0, stream>>>(hidden, row2tok, xperm);
    gemm1_fb_kernel<<<dim3(36, EI_DIM / 128), 256, 0, stream>>>(
        xperm, gateW, upW, meta, inter);
    gemm2_fb_kernel<<<dim3(36, H_DIM / 128), 256, 0, stream>>>(
        inter, downW, meta, row2tok, out);
  }
}